// Round 6
// baseline (3717.929 us; speedup 1.0000x reference)
//
#include <hip/hip_runtime.h>
#include <hip/hip_bf16.h>

typedef unsigned int u32;
typedef unsigned short u16;

#define DF __device__ __forceinline__

DF float bf2f(u16 v){ u32 t = ((u32)v)<<16; return __builtin_bit_cast(float, t); }
DF u16 f2bf(float f){
  u32 t = __builtin_bit_cast(u32, f);
  t += 0x7fffu + ((t>>16)&1u);
  return (u16)(t>>16);
}
DF float lo16(u32 p){ return __builtin_bit_cast(float, p<<16); }
DF float hi16(u32 p){ return __builtin_bit_cast(float, p & 0xffff0000u); }
DF u32 pack2(float a, float b){ return (u32)f2bf(a) | (((u32)f2bf(b))<<16); }
DF float gelu(float x){ return 0.5f*x*(1.0f+erff(x*0.70710678118654752f)); }

// ---------------------------------------------------------------------------
// K0: qkv/proj weight transpose (f32 -> bf16), staged in FRONT of d_out
// (d_out free until mlp_k overwrites it; attn_k consumes these first).
// qwT : [c(96)][o(288)]   pwT : [c(96)][o(96)]   (73.7KB total)
// ---------------------------------------------------------------------------
__global__ void wprep_k(const float* __restrict__ qkvw, const float* __restrict__ projw,
                        u16* __restrict__ qwT, u16* __restrict__ pwT)
{
  int e = blockIdx.x*256 + threadIdx.x;
  if (e < 27648){
    int c = e/288, o = e%288;
    qwT[e] = f2bf(qkvw[o*96 + c]);
  } else if (e < 36864){
    int r = e - 27648;
    int c = r/96, o = r%96;
    pwT[r] = f2bf(projw[o*96 + c]);
  }
}

// ---------------------------------------------------------------------------
// K1: fused windowed attention. One block per 7x7 window.
// LN1 + roll(+3) gather + QKV + relpos bias + NDWI mask + softmax + PV +
// proj + roll(-4) scatter + residual.  LDS 62.6KB.
// Inputs f32; x1 out bf16 (ws).
// ---------------------------------------------------------------------------
__global__ __launch_bounds__(256,2) void attn_k(
    const float* __restrict__ x, const float* __restrict__ ndwi,
    const float* __restrict__ n1g, const float* __restrict__ n1b,
    const u16* __restrict__ qwT, const float* __restrict__ qb,
    const u16* __restrict__ pwT, const float* __restrict__ pb,
    const float* __restrict__ rpbt, u16* __restrict__ x1o)
{
  __shared__ float xw[49*97];        // LN'd window input; later attention output
  __shared__ float ql[49*97];        // q (f32)
  __shared__ u32 kp[49*49];          // k packed bf16 pairs, row stride 49
  __shared__ u32 vp[49*49];          // v packed
  __shared__ float rpb[1352];
  __shared__ float mw[49];
  const int tid = threadIdx.x;
  const int blk = blockIdx.x;
  const int b = blk >> 10, wy = (blk>>5)&31, wx = blk&31;

  for (int i = tid; i < 1352; i += 256) rpb[i] = rpbt[i];

  // gather shifted window (roll +3) + NDWI values
  for (int e = tid; e < 49*48; e += 256){
    int t = e/48, c2 = e%48;
    int ty = t/7, tx = t%7;
    int sy = wy*7 + ty - 3; if (sy < 0) sy += 224;
    int sx = wx*7 + tx - 3; if (sx < 0) sx += 224;
    size_t base = ((size_t)((b*224 + sy)*224 + sx))*96;
    float2 p = *(const float2*)(x + base + c2*2);
    xw[t*97 + c2*2]   = p.x;
    xw[t*97 + c2*2+1] = p.y;
    if (c2 == 0) mw[t] = ndwi[(size_t)b*50176 + sy*224 + sx];
  }
  __syncthreads();

  // LN1 per token
  if (tid < 49){
    float m = 0.f;
    #pragma unroll
    for (int c = 0; c < 96; c++) m += xw[tid*97+c];
    m *= (1.f/96.f);
    float v = 0.f;
    #pragma unroll
    for (int c = 0; c < 96; c++){ float d = xw[tid*97+c]-m; v += d*d; }
    float rs = rsqrtf(v*(1.f/96.f) + 1e-5f);
    #pragma unroll
    for (int c = 0; c < 96; c++)
      xw[tid*97+c] = (xw[tid*97+c]-m)*rs*n1g[c] + n1b[c];
  }
  __syncthreads();

  // QKV: task = (token, 8-wide output group)
  for (int task = tid; task < 49*36; task += 256){
    int t = task/36, og = task - (task/36)*36;
    int o0 = og*8;
    float acc[8];
    #pragma unroll
    for (int k = 0; k < 8; k++) acc[k] = qb[o0+k];
    #pragma unroll 4
    for (int c = 0; c < 96; c++){
      float xv = xw[t*97+c];
      uint4 wv = *(const uint4*)(qwT + (size_t)c*288 + o0);
      acc[0] += xv*lo16(wv.x); acc[1] += xv*hi16(wv.x);
      acc[2] += xv*lo16(wv.y); acc[3] += xv*hi16(wv.y);
      acc[4] += xv*lo16(wv.z); acc[5] += xv*hi16(wv.z);
      acc[6] += xv*lo16(wv.w); acc[7] += xv*hi16(wv.w);
    }
    int m3 = o0/96;                      // 0=q,1=k,2=v
    int oo = o0 - m3*96;
    if (m3 == 0){
      #pragma unroll
      for (int k = 0; k < 8; k++) ql[t*97+oo+k] = acc[k]*0.28867513459481287f;
    } else {
      u32* dst = (m3 == 1 ? kp : vp) + t*49 + oo/2;
      #pragma unroll
      for (int i = 0; i < 4; i++) dst[i] = pack2(acc[2*i], acc[2*i+1]);
    }
  }
  __syncthreads();

  // attention: task = (head, query row)
  for (int task = tid; task < 392; task += 256){
    int h = task/49, i = task - (task/49)*49;
    int iy = i/7, ix = i%7;
    float q[12];
    const float* qr = &ql[i*97 + h*12];
    #pragma unroll
    for (int d = 0; d < 12; d++) q[d] = qr[d];
    float s[49]; float mx = -1e30f;
    float mi = mw[i];
    #pragma unroll
    for (int j = 0; j < 49; j++){
      const u32* kr = &kp[j*49 + h*6];
      float a = 0.f;
      #pragma unroll
      for (int d6 = 0; d6 < 6; d6++){
        u32 w = kr[d6];
        a += q[2*d6]*lo16(w) + q[2*d6+1]*hi16(w);
      }
      const int jy = j/7, jx = j%7;
      a += rpb[((iy-jy+6)*13 + (ix-jx+6))*8 + h];
      a = (mi != mw[j]) ? a - 100.f : a;
      s[j] = a; mx = fmaxf(mx, a);
    }
    float l = 0.f;
    #pragma unroll
    for (int j = 0; j < 49; j++){ float p = __expf(s[j]-mx); s[j] = p; l += p; }
    float rl = 1.f/l;
    float o[12];
    #pragma unroll
    for (int d = 0; d < 12; d++) o[d] = 0.f;
    #pragma unroll
    for (int j = 0; j < 49; j++){
      const u32* vr = &vp[j*49 + h*6];
      float p = s[j];
      #pragma unroll
      for (int d6 = 0; d6 < 6; d6++){
        u32 w = vr[d6];
        o[2*d6]   += p*lo16(w);
        o[2*d6+1] += p*hi16(w);
      }
    }
    float* orow = &xw[i*97 + h*12];
    #pragma unroll
    for (int d = 0; d < 12; d++) orow[d] = o[d]*rl;
  }
  __syncthreads();

  // proj + reverse roll (-4) + residual (f32) -> x1 (ws, bf16)
  for (int task = tid; task < 49*12; task += 256){
    int t = task/12, og = task - (task/12)*12;
    int o0 = og*8;
    float acc[8];
    #pragma unroll
    for (int k = 0; k < 8; k++) acc[k] = pb[o0+k];
    #pragma unroll 4
    for (int c = 0; c < 96; c++){
      float xv = xw[t*97+c];
      uint4 wv = *(const uint4*)(pwT + (size_t)c*96 + o0);
      acc[0] += xv*lo16(wv.x); acc[1] += xv*hi16(wv.x);
      acc[2] += xv*lo16(wv.y); acc[3] += xv*hi16(wv.y);
      acc[4] += xv*lo16(wv.z); acc[5] += xv*hi16(wv.z);
      acc[6] += xv*lo16(wv.w); acc[7] += xv*hi16(wv.w);
    }
    int ty = t/7, tx = t%7;
    int dy = wy*7 + ty - 4; if (dy < 0) dy += 224;
    int dx = wx*7 + tx - 4; if (dx < 0) dx += 224;
    size_t base = ((size_t)((b*224+dy)*224+dx))*96 + o0;
    float4 r0 = *(const float4*)(x + base);
    float4 r1 = *(const float4*)(x + base + 4);
    uint4 ov;
    ov.x = pack2(acc[0]+r0.x, acc[1]+r0.y);
    ov.y = pack2(acc[2]+r0.z, acc[3]+r0.w);
    ov.z = pack2(acc[4]+r1.x, acc[5]+r1.y);
    ov.w = pack2(acc[6]+r1.z, acc[7]+r1.w);
    *(uint4*)(x1o + base) = ov;
  }
}

// ---------------------------------------------------------------------------
// K2: fused LN2 + MLP (96->384 GELU ->96) + residual. x1(ws,bf16) -> x2(d_out,F32).
// f32 weights staged to LDS bf16-packed in four 96-hidden quarters. LDS 39.6KB.
// ---------------------------------------------------------------------------
__global__ __launch_bounds__(256,2) void mlp_k(
    const u16* __restrict__ x1, const float* __restrict__ w1, const float* __restrict__ b1,
    const float* __restrict__ w2, const float* __restrict__ b2,
    const float* __restrict__ g2, const float* __restrict__ bb2,
    float* __restrict__ x2o)
{
  __shared__ u32 w1l[96*48];   // [hh][c-pair]
  __shared__ u32 w2l[96*48];   // transposed [hh][c-pair]
  __shared__ float b1l[384];
  __shared__ float sm[96*3];   // b2,g2,bb2
  const int tid = threadIdx.x;
  for (int i = tid; i < 384; i += 256) b1l[i] = b1[i];
  if (tid < 96){
    sm[tid]     = b2[tid];
    sm[96+tid]  = g2[tid];
    sm[192+tid] = bb2[tid];
  }
  size_t tok = (size_t)blockIdx.x*256 + tid;
  const u16* xrow = x1 + tok*96;
  float xn[96];
  #pragma unroll
  for (int qd = 0; qd < 12; qd++){
    uint4 v = ((const uint4*)xrow)[qd];
    xn[qd*8+0]=lo16(v.x); xn[qd*8+1]=hi16(v.x);
    xn[qd*8+2]=lo16(v.y); xn[qd*8+3]=hi16(v.y);
    xn[qd*8+4]=lo16(v.z); xn[qd*8+5]=hi16(v.z);
    xn[qd*8+6]=lo16(v.w); xn[qd*8+7]=hi16(v.w);
  }
  float x1v[96];
  #pragma unroll
  for (int c = 0; c < 96; c++) x1v[c] = xn[c];
  float m = 0.f;
  #pragma unroll
  for (int c = 0; c < 96; c++) m += xn[c];
  m *= (1.f/96.f);
  float vv = 0.f;
  #pragma unroll
  for (int c = 0; c < 96; c++){ float d = xn[c]-m; vv += d*d; }
  float rs = rsqrtf(vv*(1.f/96.f)+1e-5f);
  __syncthreads();
  #pragma unroll
  for (int c = 0; c < 96; c++) xn[c] = (xn[c]-m)*rs*sm[96+c] + sm[192+c];

  float out[96];
  #pragma unroll
  for (int c = 0; c < 96; c++) out[c] = 0.f;

  for (int quarter = 0; quarter < 4; quarter++){
    const int h0 = quarter*96;
    __syncthreads();
    for (int e = tid; e < 4608; e += 256){
      int hh = e/48, c2 = e - (e/48)*48;
      float2 a = *(const float2*)(w1 + (size_t)(h0+hh)*96 + 2*c2);
      w1l[e] = pack2(a.x, a.y);
      w2l[e] = pack2(w2[(size_t)(2*c2)*384 + h0 + hh],
                     w2[(size_t)(2*c2+1)*384 + h0 + hh]);
    }
    __syncthreads();
    for (int hh = 0; hh < 96; hh += 4){
      float a[4];
      #pragma unroll
      for (int k = 0; k < 4; k++) a[k] = b1l[h0+hh+k];
      #pragma unroll
      for (int c8 = 0; c8 < 12; c8++){
        #pragma unroll
        for (int k = 0; k < 4; k++){
          uint4 wv = *(const uint4*)&w1l[(hh+k)*48 + c8*4];
          a[k] += xn[c8*8+0]*lo16(wv.x) + xn[c8*8+1]*hi16(wv.x)
                + xn[c8*8+2]*lo16(wv.y) + xn[c8*8+3]*hi16(wv.y)
                + xn[c8*8+4]*lo16(wv.z) + xn[c8*8+5]*hi16(wv.z)
                + xn[c8*8+6]*lo16(wv.w) + xn[c8*8+7]*hi16(wv.w);
        }
      }
      float g[4];
      #pragma unroll
      for (int k = 0; k < 4; k++) g[k] = gelu(a[k]);
      #pragma unroll
      for (int c8 = 0; c8 < 12; c8++){
        #pragma unroll
        for (int k = 0; k < 4; k++){
          uint4 wv = *(const uint4*)&w2l[(hh+k)*48 + c8*4];
          out[c8*8+0] += g[k]*lo16(wv.x); out[c8*8+1] += g[k]*hi16(wv.x);
          out[c8*8+2] += g[k]*lo16(wv.y); out[c8*8+3] += g[k]*hi16(wv.y);
          out[c8*8+4] += g[k]*lo16(wv.z); out[c8*8+5] += g[k]*hi16(wv.z);
          out[c8*8+6] += g[k]*lo16(wv.w); out[c8*8+7] += g[k]*hi16(wv.w);
        }
      }
    }
  }
  // residual + b2 -> x2 (d_out, f32)
  float* orow = x2o + tok*96;
  #pragma unroll
  for (int q4 = 0; q4 < 24; q4++){
    float4 pv;
    pv.x = x1v[q4*4+0] + out[q4*4+0] + sm[q4*4+0];
    pv.y = x1v[q4*4+1] + out[q4*4+1] + sm[q4*4+1];
    pv.z = x1v[q4*4+2] + out[q4*4+2] + sm[q4*4+2];
    pv.w = x1v[q4*4+3] + out[q4*4+3] + sm[q4*4+3];
    ((float4*)orow)[q4] = pv;
  }
}

// ---------------------------------------------------------------------------
// K3a: per-pixel LN3 + 3x3 conv (dil 1, pad 1) + bias + BN + GELU.
// src = x2 (f32, d_out), dst = h1 (bf16, ws). LDS 53.7KB.
// ---------------------------------------------------------------------------
__global__ __launch_bounds__(256,2) void conv1_k(
    const float* __restrict__ src, const float* __restrict__ wOIHW,
    const float* __restrict__ cb, const float* __restrict__ bng, const float* __restrict__ bnb,
    const float* __restrict__ bnm, const float* __restrict__ bnv,
    const float* __restrict__ g3, const float* __restrict__ b3,
    u16* __restrict__ dst)
{
  constexpr int DIL = 1, SY = 10, SX = 18;
  __shared__ u32 intile[SY*SX*49];   // [pixel][c-pair], stride 49 dwords
  __shared__ u32 wsl[4608];          // one tap: [c][o-pair]
  const int tid = threadIdx.x;
  const int bx = blockIdx.x*16, by = blockIdx.y*8, b = blockIdx.z;
  const int gy0 = by - DIL, gx0 = bx - DIL;
  for (int e = tid; e < SY*SX*48; e += 256){
    int p = e/48, c2 = e - (e/48)*48;
    int y = p/SX, xx = p - (p/SX)*SX;
    int gy = gy0+y, gx = gx0+xx;
    u32 v = 0;
    if (gy >= 0 && gy < 224 && gx >= 0 && gx < 224){
      float2 rd = *(const float2*)(src + ((size_t)((b*224+gy)*224+gx))*96 + c2*2);
      v = pack2(rd.x, rd.y);
    }
    intile[p*49 + c2] = v;
  }
  __syncthreads();
  // per-pixel LayerNorm (in-image pixels only; halo stays ZERO = zero-pad of
  // the LN3 output image, matching the reference conv padding).
  for (int p = tid; p < SY*SX; p += 256){
    int y = p/SX, xx = p - (p/SX)*SX;
    int gy = gy0+y, gx = gx0+xx;
    if (gy >= 0 && gy < 224 && gx >= 0 && gx < 224){
      u32* row = &intile[p*49];
      float m = 0.f;
      #pragma unroll
      for (int c2 = 0; c2 < 48; c2++){ u32 v = row[c2]; m += lo16(v)+hi16(v); }
      m *= (1.f/96.f);
      float var = 0.f;
      #pragma unroll
      for (int c2 = 0; c2 < 48; c2++){
        u32 v = row[c2];
        float d0 = lo16(v)-m, d1 = hi16(v)-m;
        var += d0*d0 + d1*d1;
      }
      float rs = rsqrtf(var*(1.f/96.f)+1e-5f);
      #pragma unroll
      for (int c2 = 0; c2 < 48; c2++){
        u32 v = row[c2];
        float2 gg = *(const float2*)(g3 + 2*c2);
        float2 bb = *(const float2*)(b3 + 2*c2);
        row[c2] = pack2((lo16(v)-m)*rs*gg.x+bb.x,
                        (hi16(v)-m)*rs*gg.y+bb.y);
      }
    }
  }
  const int pxg = tid & 31, og = tid >> 5;
  const int px8 = pxg & 15, py8 = pxg >> 4;
  const int o0 = og*12;
  float acc[4][12];
  #pragma unroll
  for (int a = 0; a < 4; a++)
    #pragma unroll
    for (int j = 0; j < 12; j++) acc[a][j] = 0.f;

  for (int ky = 0; ky < 3; ky++)
  for (int kx = 0; kx < 3; kx++){
    const int tap = ky*3+kx;
    __syncthreads();
    for (int e = tid; e < 4608; e += 256){
      int c = e/48, o2 = e - (e/48)*48;
      float wa = wOIHW[((2*o2)*96 + c)*9 + tap];
      float wb = wOIHW[((2*o2+1)*96 + c)*9 + tap];
      wsl[e] = pack2(wa, wb);
    }
    __syncthreads();
    for (int c2 = 0; c2 < 48; c2++){
      u32 iv[4];
      #pragma unroll
      for (int a = 0; a < 4; a++)
        iv[a] = intile[((py8+2*a+ky*DIL)*SX + (px8+kx*DIL))*49 + c2];
      const u32* wr0 = &wsl[(2*c2)*48 + og*6];
      const u32* wr1 = &wsl[(2*c2+1)*48 + og*6];
      float w0[12], w1f[12];
      #pragma unroll
      for (int d = 0; d < 6; d++){
        w0[2*d]=lo16(wr0[d]);  w0[2*d+1]=hi16(wr0[d]);
        w1f[2*d]=lo16(wr1[d]); w1f[2*d+1]=hi16(wr1[d]);
      }
      #pragma unroll
      for (int a = 0; a < 4; a++){
        float i0 = lo16(iv[a]), i1 = hi16(iv[a]);
        #pragma unroll
        for (int j = 0; j < 12; j++) acc[a][j] += i0*w0[j] + i1*w1f[j];
      }
    }
  }
  float sc[12], mm[12], bb[12], cbv[12];
  #pragma unroll
  for (int j = 0; j < 12; j++){
    sc[j] = bng[o0+j]*rsqrtf(bnv[o0+j]+1e-5f);
    mm[j] = bnm[o0+j]; bb[j] = bnb[o0+j]; cbv[j] = cb[o0+j];
  }
  #pragma unroll
  for (int a = 0; a < 4; a++){
    int gy = by + py8 + 2*a, gx = bx + px8;
    size_t base = ((size_t)((b*224+gy)*224+gx))*96 + o0;
    #pragma unroll
    for (int d = 0; d < 6; d++){
      float t0 = (acc[a][2*d]   + cbv[2*d]   - mm[2*d])  *sc[2*d]   + bb[2*d];
      float t1 = (acc[a][2*d+1] + cbv[2*d+1] - mm[2*d+1])*sc[2*d+1] + bb[2*d+1];
      *(u32*)(dst + base + 2*d) = pack2(gelu(t0), gelu(t1));
    }
  }
}

// ---------------------------------------------------------------------------
// K3b: 3x3 conv (dil 2, pad 2) + bias + BN + GELU + residual(x2) -> final f32.
// src = h1 (bf16, ws); resid/dst alias d_out (pointwise same-element
// read-then-write per thread -> no restrict). LDS 64.0KB.
// ---------------------------------------------------------------------------
__global__ __launch_bounds__(256,2) void conv2_k(
    const u16* __restrict__ src, const float* __restrict__ wOIHW,
    const float* __restrict__ cb, const float* __restrict__ bng, const float* __restrict__ bnb,
    const float* __restrict__ bnm, const float* __restrict__ bnv,
    const float* resid, float* dst)
{
  constexpr int DIL = 2, SY = 12, SX = 20;
  __shared__ u32 intile[SY*SX*49];
  __shared__ u32 wsl[4608];
  const int tid = threadIdx.x;
  const int bx = blockIdx.x*16, by = blockIdx.y*8, b = blockIdx.z;
  const int gy0 = by - DIL, gx0 = bx - DIL;
  for (int e = tid; e < SY*SX*48; e += 256){
    int p = e/48, c2 = e - (e/48)*48;
    int y = p/SX, xx = p - (p/SX)*SX;
    int gy = gy0+y, gx = gx0+xx;
    u32 v = 0;
    if (gy >= 0 && gy < 224 && gx >= 0 && gx < 224)
      v = *(const u32*)(src + ((size_t)((b*224+gy)*224+gx))*96 + c2*2);
    intile[p*49 + c2] = v;
  }
  const int pxg = tid & 31, og = tid >> 5;
  const int px8 = pxg & 15, py8 = pxg >> 4;
  const int o0 = og*12;
  float acc[4][12];
  #pragma unroll
  for (int a = 0; a < 4; a++)
    #pragma unroll
    for (int j = 0; j < 12; j++) acc[a][j] = 0.f;

  for (int ky = 0; ky < 3; ky++)
  for (int kx = 0; kx < 3; kx++){
    const int tap = ky*3+kx;
    __syncthreads();
    for (int e = tid; e < 4608; e += 256){
      int c = e/48, o2 = e - (e/48)*48;
      float wa = wOIHW[((2*o2)*96 + c)*9 + tap];
      float wb = wOIHW[((2*o2+1)*96 + c)*9 + tap];
      wsl[e] = pack2(wa, wb);
    }
    __syncthreads();
    for (int c2 = 0; c2 < 48; c2++){
      u32 iv[4];
      #pragma unroll
      for (int a = 0; a < 4; a++)
        iv[a] = intile[((py8+2*a+ky*DIL)*SX + (px8+kx*DIL))*49 + c2];
      const u32* wr0 = &wsl[(2*c2)*48 + og*6];
      const u32* wr1 = &wsl[(2*c2+1)*48 + og*6];
      float w0[12], w1f[12];
      #pragma unroll
      for (int d = 0; d < 6; d++){
        w0[2*d]=lo16(wr0[d]);  w0[2*d+1]=hi16(wr0[d]);
        w1f[2*d]=lo16(wr1[d]); w1f[2*d+1]=hi16(wr1[d]);
      }
      #pragma unroll
      for (int a = 0; a < 4; a++){
        float i0 = lo16(iv[a]), i1 = hi16(iv[a]);
        #pragma unroll
        for (int j = 0; j < 12; j++) acc[a][j] += i0*w0[j] + i1*w1f[j];
      }
    }
  }
  float sc[12], mm[12], bb[12], cbv[12];
  #pragma unroll
  for (int j = 0; j < 12; j++){
    sc[j] = bng[o0+j]*rsqrtf(bnv[o0+j]+1e-5f);
    mm[j] = bnm[o0+j]; bb[j] = bnb[o0+j]; cbv[j] = cb[o0+j];
  }
  #pragma unroll
  for (int a = 0; a < 4; a++){
    int gy = by + py8 + 2*a, gx = bx + px8;
    size_t base = ((size_t)((b*224+gy)*224+gx))*96 + o0;
    float4 r0 = *(const float4*)(resid + base);
    float4 r1 = *(const float4*)(resid + base + 4);
    float4 r2 = *(const float4*)(resid + base + 8);
    float ov[12];
    #pragma unroll
    for (int j = 0; j < 12; j++){
      float t = (acc[a][j] + cbv[j] - mm[j])*sc[j] + bb[j];
      ov[j] = gelu(t);
    }
    float4 s0, s1, s2;
    s0.x = ov[0]+r0.x;  s0.y = ov[1]+r0.y;  s0.z = ov[2]+r0.z;  s0.w = ov[3]+r0.w;
    s1.x = ov[4]+r1.x;  s1.y = ov[5]+r1.y;  s1.z = ov[6]+r1.z;  s1.w = ov[7]+r1.w;
    s2.x = ov[8]+r2.x;  s2.y = ov[9]+r2.y;  s2.z = ov[10]+r2.z; s2.w = ov[11]+r2.w;
    *(float4*)(dst + base)     = s0;
    *(float4*)(dst + base + 4) = s1;
    *(float4*)(dst + base + 8) = s2;
  }
}

// ---------------------------------------------------------------------------
extern "C" void kernel_launch(void* const* d_in, const int* in_sizes, int n_in,
                              void* d_out, int out_size, void* d_ws, size_t ws_size,
                              hipStream_t stream)
{
  const float* x    = (const float*)d_in[0];
  const float* ndwi = (const float*)d_in[1];
  const float* n1g  = (const float*)d_in[2];
  const float* n1b  = (const float*)d_in[3];
  const float* qkvw = (const float*)d_in[4];
  const float* qkvb = (const float*)d_in[5];
  const float* projw= (const float*)d_in[6];
  const float* projb= (const float*)d_in[7];
  const float* rpbt = (const float*)d_in[8];
  const float* n2g  = (const float*)d_in[9];
  const float* n2b  = (const float*)d_in[10];
  const float* w1   = (const float*)d_in[11];
  const float* b1   = (const float*)d_in[12];
  const float* w2   = (const float*)d_in[13];
  const float* b2   = (const float*)d_in[14];
  const float* n3g  = (const float*)d_in[15];
  const float* n3b  = (const float*)d_in[16];
  const float* c1w  = (const float*)d_in[17];
  const float* c1b  = (const float*)d_in[18];
  const float* bn1g = (const float*)d_in[19];
  const float* bn1b = (const float*)d_in[20];
  const float* bn1m = (const float*)d_in[21];
  const float* bn1v = (const float*)d_in[22];
  const float* c2w  = (const float*)d_in[23];
  const float* c2b  = (const float*)d_in[24];
  const float* bn2g = (const float*)d_in[25];
  const float* bn2b = (const float*)d_in[26];
  const float* bn2m = (const float*)d_in[27];
  const float* bn2v = (const float*)d_in[28];

  int B = out_size / (224*224*96);
  if (B < 1 || B > 64) B = 4;

  // Memory plan:
  //   d_out (f32): [qwT|pwT bf16 staging 73.7KB] -> x2 (f32) -> final (f32)
  //   d_ws  (bf16): x1 (attn out) -> h1 (conv1 out)   [38.5MB]
  u16*   wsA = (u16*)d_ws;
  u16*   qwT = (u16*)d_out;
  u16*   pwT = qwT + 27648;
  float* xo  = (float*)d_out;

  wprep_k<<<dim3(144), dim3(256), 0, stream>>>(qkvw, projw, qwT, pwT);
  attn_k<<<dim3(B*1024), dim3(256), 0, stream>>>(x, ndwi, n1g, n1b, qwT, qkvb, pwT, projb, rpbt, wsA);
  mlp_k<<<dim3(B*196), dim3(256), 0, stream>>>(wsA, w1, b1, w2, b2, n2g, n2b, xo);
  conv1_k<<<dim3(14,28,B), dim3(256), 0, stream>>>(xo, c1w, c1b, bn1g, bn1b, bn1m, bn1v, n3g, n3b, wsA);
  conv2_k<<<dim3(14,28,B), dim3(256), 0, stream>>>(wsA, c2w, c2b, bn2g, bn2b, bn2m, bn2v, xo, xo);
}

// Round 7
// 3145.531 us; speedup vs baseline: 1.1820x; 1.1820x over previous
//
#include <hip/hip_runtime.h>
#include <hip/hip_bf16.h>

typedef unsigned int u32;
typedef unsigned short u16;

#define DF __device__ __forceinline__

DF float bf2f(u16 v){ u32 t = ((u32)v)<<16; return __builtin_bit_cast(float, t); }
DF u16 f2bf(float f){
  u32 t = __builtin_bit_cast(u32, f);
  t += 0x7fffu + ((t>>16)&1u);
  return (u16)(t>>16);
}
DF float lo16(u32 p){ return __builtin_bit_cast(float, p<<16); }
DF float hi16(u32 p){ return __builtin_bit_cast(float, p & 0xffff0000u); }
DF u32 pack2(float a, float b){ return (u32)f2bf(a) | (((u32)f2bf(b))<<16); }
DF float gelu(float x){ return 0.5f*x*(1.0f+erff(x*0.70710678118654752f)); }

// ---------------------------------------------------------------------------
// K0: qkv/proj weight transpose (f32 -> bf16), staged in FRONT of d_out.
// qwT : [c(96)][o(288)]   pwT : [c(96)][o(96)]
// ---------------------------------------------------------------------------
__global__ void wprep_k(const float* __restrict__ qkvw, const float* __restrict__ projw,
                        u16* __restrict__ qwT, u16* __restrict__ pwT)
{
  int e = blockIdx.x*256 + threadIdx.x;
  if (e < 27648){
    int c = e/288, o = e%288;
    qwT[e] = f2bf(qkvw[o*96 + c]);
  } else if (e < 36864){
    int r = e - 27648;
    int c = r/96, o = r%96;
    pwT[r] = f2bf(projw[o*96 + c]);
  }
}

// ---------------------------------------------------------------------------
// K1: fused windowed attention. One block (4 waves) per 7x7 window.
// QKV/proj phases: wave <-> output-group, lane <-> token, so weight uint4
// loads are wave-broadcast (one address/wave) -> 55KB weight traffic/block.
// LDS 62.8KB -> 2 blocks/CU.
// ---------------------------------------------------------------------------
__global__ __launch_bounds__(256,2) void attn_k(
    const float* __restrict__ x, const float* __restrict__ ndwi,
    const float* __restrict__ n1g, const float* __restrict__ n1b,
    const u16* __restrict__ qwT, const float* __restrict__ qb,
    const u16* __restrict__ pwT, const float* __restrict__ pb,
    const float* __restrict__ rpbt, u16* __restrict__ x1o)
{
  __shared__ float xw[49*97];        // LN'd window input; later attention output
  __shared__ float ql[49*97];        // q (f32)
  __shared__ u32 kp[49*49];          // k packed bf16 pairs, row stride 49
  __shared__ u32 vp[49*49];          // v packed
  __shared__ float rpb[1352];
  __shared__ float mw[49];
  const int tid = threadIdx.x;
  const int blk = blockIdx.x;
  const int b = blk >> 10, wy = (blk>>5)&31, wx = blk&31;
  const int wv_ = tid >> 6;          // wave 0..3
  const int ln  = tid & 63;          // lane
  const int lnc = ln < 49 ? ln : 48; // clamped token index (avoid LDS OOB)

  for (int i = tid; i < 1352; i += 256) rpb[i] = rpbt[i];

  // gather shifted window (roll +3) + NDWI values
  for (int e = tid; e < 49*48; e += 256){
    int t = e/48, c2 = e%48;
    int ty = t/7, tx = t%7;
    int sy = wy*7 + ty - 3; if (sy < 0) sy += 224;
    int sx = wx*7 + tx - 3; if (sx < 0) sx += 224;
    size_t base = ((size_t)((b*224 + sy)*224 + sx))*96;
    float2 p = *(const float2*)(x + base + c2*2);
    xw[t*97 + c2*2]   = p.x;
    xw[t*97 + c2*2+1] = p.y;
    if (c2 == 0) mw[t] = ndwi[(size_t)b*50176 + sy*224 + sx];
  }
  __syncthreads();

  // LN1: 4 lanes per token (tid < 196)
  if (tid < 196){
    const int t = tid >> 2, p = tid & 3;
    float c[24];
    #pragma unroll
    for (int j = 0; j < 24; j++) c[j] = xw[t*97 + p*24 + j];
    float s = 0.f, s2 = 0.f;
    #pragma unroll
    for (int j = 0; j < 24; j++){ s += c[j]; s2 += c[j]*c[j]; }
    s  += __shfl_xor(s, 1);  s  += __shfl_xor(s, 2);
    s2 += __shfl_xor(s2, 1); s2 += __shfl_xor(s2, 2);
    float m = s*(1.f/96.f);
    float rs = rsqrtf(s2*(1.f/96.f) - m*m + 1e-5f);
    #pragma unroll
    for (int j = 0; j < 24; j++)
      xw[t*97 + p*24 + j] = (c[j]-m)*rs*n1g[p*24+j] + n1b[p*24+j];
  }
  __syncthreads();

  // QKV: wave w handles og = w*9..w*9+8; lane = token
  for (int ogi = 0; ogi < 9; ogi++){
    const int og = wv_*9 + ogi;
    const int o0 = og*8;
    float acc[8];
    #pragma unroll
    for (int k = 0; k < 8; k++) acc[k] = qb[o0+k];
    #pragma unroll 4
    for (int c = 0; c < 96; c++){
      uint4 wvv = *(const uint4*)(qwT + (size_t)c*288 + o0);  // wave-broadcast
      float xv = xw[lnc*97 + c];
      acc[0] += xv*lo16(wvv.x); acc[1] += xv*hi16(wvv.x);
      acc[2] += xv*lo16(wvv.y); acc[3] += xv*hi16(wvv.y);
      acc[4] += xv*lo16(wvv.z); acc[5] += xv*hi16(wvv.z);
      acc[6] += xv*lo16(wvv.w); acc[7] += xv*hi16(wvv.w);
    }
    if (ln < 49){
      int m3 = o0/96;                  // 0=q,1=k,2=v
      int oo = o0 - m3*96;
      if (m3 == 0){
        #pragma unroll
        for (int k = 0; k < 8; k++) ql[ln*97+oo+k] = acc[k]*0.28867513459481287f;
      } else {
        u32* dst = (m3 == 1 ? kp : vp) + ln*49 + oo/2;
        #pragma unroll
        for (int i = 0; i < 4; i++) dst[i] = pack2(acc[2*i], acc[2*i+1]);
      }
    }
  }
  __syncthreads();

  // attention: task = (head, query row)
  for (int task = tid; task < 392; task += 256){
    int h = task/49, i = task - (task/49)*49;
    int iy = i/7, ix = i%7;
    float q[12];
    const float* qr = &ql[i*97 + h*12];
    #pragma unroll
    for (int d = 0; d < 12; d++) q[d] = qr[d];
    float s[49]; float mx = -1e30f;
    float mi = mw[i];
    #pragma unroll
    for (int j = 0; j < 49; j++){
      const u32* kr = &kp[j*49 + h*6];
      float a = 0.f;
      #pragma unroll
      for (int d6 = 0; d6 < 6; d6++){
        u32 w = kr[d6];
        a += q[2*d6]*lo16(w) + q[2*d6+1]*hi16(w);
      }
      const int jy = j/7, jx = j%7;
      a += rpb[((iy-jy+6)*13 + (ix-jx+6))*8 + h];
      a = (mi != mw[j]) ? a - 100.f : a;
      s[j] = a; mx = fmaxf(mx, a);
    }
    float l = 0.f;
    #pragma unroll
    for (int j = 0; j < 49; j++){ float p = __expf(s[j]-mx); s[j] = p; l += p; }
    float rl = 1.f/l;
    float o[12];
    #pragma unroll
    for (int d = 0; d < 12; d++) o[d] = 0.f;
    #pragma unroll
    for (int j = 0; j < 49; j++){
      const u32* vr = &vp[j*49 + h*6];
      float p = s[j];
      #pragma unroll
      for (int d6 = 0; d6 < 6; d6++){
        u32 w = vr[d6];
        o[2*d6]   += p*lo16(w);
        o[2*d6+1] += p*hi16(w);
      }
    }
    float* orow = &xw[i*97 + h*12];
    #pragma unroll
    for (int d = 0; d < 12; d++) orow[d] = o[d]*rl;
  }
  __syncthreads();

  // proj: wave w handles og = w*3..w*3+2; lane = token.
  // reverse roll (-4) + residual (f32 x) -> x1 (ws, bf16)
  for (int ogi = 0; ogi < 3; ogi++){
    const int og = wv_*3 + ogi;
    const int o0 = og*8;
    float acc[8];
    #pragma unroll
    for (int k = 0; k < 8; k++) acc[k] = pb[o0+k];
    #pragma unroll 4
    for (int c = 0; c < 96; c++){
      uint4 wvv = *(const uint4*)(pwT + (size_t)c*96 + o0);   // wave-broadcast
      float xv = xw[lnc*97 + c];
      acc[0] += xv*lo16(wvv.x); acc[1] += xv*hi16(wvv.x);
      acc[2] += xv*lo16(wvv.y); acc[3] += xv*hi16(wvv.y);
      acc[4] += xv*lo16(wvv.z); acc[5] += xv*hi16(wvv.z);
      acc[6] += xv*lo16(wvv.w); acc[7] += xv*hi16(wvv.w);
    }
    if (ln < 49){
      int ty = ln/7, tx = ln%7;
      int dy = wy*7 + ty - 4; if (dy < 0) dy += 224;
      int dx = wx*7 + tx - 4; if (dx < 0) dx += 224;
      size_t base = ((size_t)((b*224+dy)*224+dx))*96 + o0;
      float4 r0 = *(const float4*)(x + base);
      float4 r1 = *(const float4*)(x + base + 4);
      uint4 ov;
      ov.x = pack2(acc[0]+r0.x, acc[1]+r0.y);
      ov.y = pack2(acc[2]+r0.z, acc[3]+r0.w);
      ov.z = pack2(acc[4]+r1.x, acc[5]+r1.y);
      ov.w = pack2(acc[6]+r1.z, acc[7]+r1.w);
      *(uint4*)(x1o + base) = ov;
    }
  }
}

// ---------------------------------------------------------------------------
// K2: fused LN2 + MLP (96->384 GELU ->96) + residual. x1(ws,bf16) -> x2(d_out,f32).
// Block-cooperative: 64 tokens/block; hidden processed in 4 chunks of 96.
// Per-thread register tile 4 tok x 6 ch (24 acc). LDS 64.2KB, no spills.
// ---------------------------------------------------------------------------
__global__ __launch_bounds__(256,2) void mlp_k(
    const u16* __restrict__ x1, const float* __restrict__ w1, const float* __restrict__ b1,
    const float* __restrict__ w2, const float* __restrict__ b2,
    const float* __restrict__ g2, const float* __restrict__ bb2,
    float* __restrict__ x2o)
{
  __shared__ u32 xt[64*49];    // LN'd x, bf16 pairs [tok][cp], stride 49
  __shared__ u32 w1l[96*49];   // chunk: [hh][cp]
  __shared__ u32 w2l[96*49];   // chunk: [oc][hp]
  __shared__ u32 hl[64*49];    // gelu(h) pairs [tok][hp], stride 49
  __shared__ float b1s[384];
  const int tid = threadIdx.x;
  const size_t t0 = (size_t)blockIdx.x * 64;

  for (int i = tid; i < 384; i += 256) b1s[i] = b1[i];

  // LN2: 4 lanes per token
  {
    const int t = tid >> 2, p = tid & 3;
    const u16* xr = x1 + (t0 + t)*96 + p*24;
    float c[24];
    #pragma unroll
    for (int q = 0; q < 3; q++){
      uint4 v = ((const uint4*)xr)[q];
      c[q*8+0]=lo16(v.x); c[q*8+1]=hi16(v.x);
      c[q*8+2]=lo16(v.y); c[q*8+3]=hi16(v.y);
      c[q*8+4]=lo16(v.z); c[q*8+5]=hi16(v.z);
      c[q*8+6]=lo16(v.w); c[q*8+7]=hi16(v.w);
    }
    float s = 0.f, s2 = 0.f;
    #pragma unroll
    for (int j = 0; j < 24; j++){ s += c[j]; s2 += c[j]*c[j]; }
    s  += __shfl_xor(s, 1);  s  += __shfl_xor(s, 2);
    s2 += __shfl_xor(s2, 1); s2 += __shfl_xor(s2, 2);
    float m = s*(1.f/96.f);
    float rs = rsqrtf(s2*(1.f/96.f) - m*m + 1e-5f);
    #pragma unroll
    for (int jj = 0; jj < 12; jj++){
      float a = (c[2*jj]  -m)*rs*g2[p*24+2*jj]   + bb2[p*24+2*jj];
      float d = (c[2*jj+1]-m)*rs*g2[p*24+2*jj+1] + bb2[p*24+2*jj+1];
      xt[t*49 + p*12 + jj] = pack2(a, d);
    }
  }

  const int ttg = tid & 15;     // tokens ttg*4+0..3
  const int hg  = tid >> 4;     // hidden/out channels hg*6+0..5
  float oacc[4][6];
  #pragma unroll
  for (int i = 0; i < 4; i++)
    #pragma unroll
    for (int k = 0; k < 6; k++) oacc[i][k] = 0.f;

  for (int q = 0; q < 4; q++){
    const int h0 = q*96;
    __syncthreads();
    // stage w1 chunk [hh][cp] and w2 chunk [oc][hp] as bf16 pairs
    for (int e = tid; e < 4608; e += 256){
      int r = e/48, cpp = e - (e/48)*48;
      float2 a1 = *(const float2*)(w1 + (size_t)(h0+r)*96 + 2*cpp);
      w1l[r*49+cpp] = pack2(a1.x, a1.y);
      float2 a2 = *(const float2*)(w2 + (size_t)r*384 + h0 + 2*cpp);
      w2l[r*49+cpp] = pack2(a2.x, a2.y);
    }
    __syncthreads();
    // phase A: h[tok][hg*6+k]
    float a[4][6];
    #pragma unroll
    for (int i = 0; i < 4; i++)
      #pragma unroll
      for (int k = 0; k < 6; k++) a[i][k] = b1s[h0 + hg*6 + k];
    for (int cp = 0; cp < 48; cp++){
      u32 xv[4], wv[6];
      #pragma unroll
      for (int i = 0; i < 4; i++) xv[i] = xt[(ttg*4+i)*49 + cp];
      #pragma unroll
      for (int k = 0; k < 6; k++) wv[k] = w1l[(hg*6+k)*49 + cp];
      #pragma unroll
      for (int i = 0; i < 4; i++){
        float xl = lo16(xv[i]), xh = hi16(xv[i]);
        #pragma unroll
        for (int k = 0; k < 6; k++)
          a[i][k] += xl*lo16(wv[k]) + xh*hi16(wv[k]);
      }
    }
    #pragma unroll
    for (int i = 0; i < 4; i++)
      #pragma unroll
      for (int p3 = 0; p3 < 3; p3++)
        hl[(ttg*4+i)*49 + hg*3 + p3] = pack2(gelu(a[i][2*p3]), gelu(a[i][2*p3+1]));
    __syncthreads();
    // phase B: out accumulate
    for (int hp = 0; hp < 48; hp++){
      u32 hv[4], wv[6];
      #pragma unroll
      for (int i = 0; i < 4; i++) hv[i] = hl[(ttg*4+i)*49 + hp];
      #pragma unroll
      for (int k = 0; k < 6; k++) wv[k] = w2l[(hg*6+k)*49 + hp];
      #pragma unroll
      for (int i = 0; i < 4; i++){
        float hlv = lo16(hv[i]), hh = hi16(hv[i]);
        #pragma unroll
        for (int k = 0; k < 6; k++)
          oacc[i][k] += hlv*lo16(wv[k]) + hh*hi16(wv[k]);
      }
    }
  }

  // epilogue: x2 = x1 + out + b2  (f32 to d_out)
  const int oc0 = hg*6;
  float b2v[6];
  #pragma unroll
  for (int k = 0; k < 6; k++) b2v[k] = b2[oc0+k];
  #pragma unroll
  for (int i = 0; i < 4; i++){
    size_t tok = t0 + ttg*4 + i;
    const u32* rr = (const u32*)(x1 + tok*96 + oc0);
    float* orow = x2o + tok*96 + oc0;
    #pragma unroll
    for (int p3 = 0; p3 < 3; p3++){
      u32 rv = rr[p3];
      float2 st;
      st.x = lo16(rv) + oacc[i][2*p3]   + b2v[2*p3];
      st.y = hi16(rv) + oacc[i][2*p3+1] + b2v[2*p3+1];
      *(float2*)(orow + 2*p3) = st;
    }
  }
}

// ---------------------------------------------------------------------------
// K3a: per-pixel LN3 + 3x3 conv (dil 1, pad 1) + bias + BN + GELU.
// src = x2 (f32, d_out), dst = h1 (bf16, ws). LDS 53.7KB.
// ---------------------------------------------------------------------------
__global__ __launch_bounds__(256,2) void conv1_k(
    const float* __restrict__ src, const float* __restrict__ wOIHW,
    const float* __restrict__ cb, const float* __restrict__ bng, const float* __restrict__ bnb,
    const float* __restrict__ bnm, const float* __restrict__ bnv,
    const float* __restrict__ g3, const float* __restrict__ b3,
    u16* __restrict__ dst)
{
  constexpr int DIL = 1, SY = 10, SX = 18;
  __shared__ u32 intile[SY*SX*49];
  __shared__ u32 wsl[4608];
  const int tid = threadIdx.x;
  const int bx = blockIdx.x*16, by = blockIdx.y*8, b = blockIdx.z;
  const int gy0 = by - DIL, gx0 = bx - DIL;
  for (int e = tid; e < SY*SX*48; e += 256){
    int p = e/48, c2 = e - (e/48)*48;
    int y = p/SX, xx = p - (p/SX)*SX;
    int gy = gy0+y, gx = gx0+xx;
    u32 v = 0;
    if (gy >= 0 && gy < 224 && gx >= 0 && gx < 224){
      float2 rd = *(const float2*)(src + ((size_t)((b*224+gy)*224+gx))*96 + c2*2);
      v = pack2(rd.x, rd.y);
    }
    intile[p*49 + c2] = v;
  }
  __syncthreads();
  for (int p = tid; p < SY*SX; p += 256){
    int y = p/SX, xx = p - (p/SX)*SX;
    int gy = gy0+y, gx = gx0+xx;
    if (gy >= 0 && gy < 224 && gx >= 0 && gx < 224){
      u32* row = &intile[p*49];
      float m = 0.f;
      #pragma unroll
      for (int c2 = 0; c2 < 48; c2++){ u32 v = row[c2]; m += lo16(v)+hi16(v); }
      m *= (1.f/96.f);
      float var = 0.f;
      #pragma unroll
      for (int c2 = 0; c2 < 48; c2++){
        u32 v = row[c2];
        float d0 = lo16(v)-m, d1 = hi16(v)-m;
        var += d0*d0 + d1*d1;
      }
      float rs = rsqrtf(var*(1.f/96.f)+1e-5f);
      #pragma unroll
      for (int c2 = 0; c2 < 48; c2++){
        u32 v = row[c2];
        float2 gg = *(const float2*)(g3 + 2*c2);
        float2 bb = *(const float2*)(b3 + 2*c2);
        row[c2] = pack2((lo16(v)-m)*rs*gg.x+bb.x,
                        (hi16(v)-m)*rs*gg.y+bb.y);
      }
    }
  }
  const int pxg = tid & 31, og = tid >> 5;
  const int px8 = pxg & 15, py8 = pxg >> 4;
  const int o0 = og*12;
  float acc[4][12];
  #pragma unroll
  for (int a = 0; a < 4; a++)
    #pragma unroll
    for (int j = 0; j < 12; j++) acc[a][j] = 0.f;

  for (int ky = 0; ky < 3; ky++)
  for (int kx = 0; kx < 3; kx++){
    const int tap = ky*3+kx;
    __syncthreads();
    for (int e = tid; e < 4608; e += 256){
      int c = e/48, o2 = e - (e/48)*48;
      float wa = wOIHW[((2*o2)*96 + c)*9 + tap];
      float wb = wOIHW[((2*o2+1)*96 + c)*9 + tap];
      wsl[e] = pack2(wa, wb);
    }
    __syncthreads();
    for (int c2 = 0; c2 < 48; c2++){
      u32 iv[4];
      #pragma unroll
      for (int a = 0; a < 4; a++)
        iv[a] = intile[((py8+2*a+ky*DIL)*SX + (px8+kx*DIL))*49 + c2];
      const u32* wr0 = &wsl[(2*c2)*48 + og*6];
      const u32* wr1 = &wsl[(2*c2+1)*48 + og*6];
      float w0[12], w1f[12];
      #pragma unroll
      for (int d = 0; d < 6; d++){
        w0[2*d]=lo16(wr0[d]);  w0[2*d+1]=hi16(wr0[d]);
        w1f[2*d]=lo16(wr1[d]); w1f[2*d+1]=hi16(wr1[d]);
      }
      #pragma unroll
      for (int a = 0; a < 4; a++){
        float i0 = lo16(iv[a]), i1 = hi16(iv[a]);
        #pragma unroll
        for (int j = 0; j < 12; j++) acc[a][j] += i0*w0[j] + i1*w1f[j];
      }
    }
  }
  float sc[12], mm[12], bb[12], cbv[12];
  #pragma unroll
  for (int j = 0; j < 12; j++){
    sc[j] = bng[o0+j]*rsqrtf(bnv[o0+j]+1e-5f);
    mm[j] = bnm[o0+j]; bb[j] = bnb[o0+j]; cbv[j] = cb[o0+j];
  }
  #pragma unroll
  for (int a = 0; a < 4; a++){
    int gy = by + py8 + 2*a, gx = bx + px8;
    size_t base = ((size_t)((b*224+gy)*224+gx))*96 + o0;
    #pragma unroll
    for (int d = 0; d < 6; d++){
      float t0 = (acc[a][2*d]   + cbv[2*d]   - mm[2*d])  *sc[2*d]   + bb[2*d];
      float t1 = (acc[a][2*d+1] + cbv[2*d+1] - mm[2*d+1])*sc[2*d+1] + bb[2*d+1];
      *(u32*)(dst + base + 2*d) = pack2(gelu(t0), gelu(t1));
    }
  }
}

// ---------------------------------------------------------------------------
// K3b: 3x3 conv (dil 2, pad 2) + bias + BN + GELU + residual(x2) -> final f32.
// src = h1 (bf16, ws); resid/dst alias d_out pointwise. LDS 64.0KB.
// ---------------------------------------------------------------------------
__global__ __launch_bounds__(256,2) void conv2_k(
    const u16* __restrict__ src, const float* __restrict__ wOIHW,
    const float* __restrict__ cb, const float* __restrict__ bng, const float* __restrict__ bnb,
    const float* __restrict__ bnm, const float* __restrict__ bnv,
    const float* resid, float* dst)
{
  constexpr int DIL = 2, SY = 12, SX = 20;
  __shared__ u32 intile[SY*SX*49];
  __shared__ u32 wsl[4608];
  const int tid = threadIdx.x;
  const int bx = blockIdx.x*16, by = blockIdx.y*8, b = blockIdx.z;
  const int gy0 = by - DIL, gx0 = bx - DIL;
  for (int e = tid; e < SY*SX*48; e += 256){
    int p = e/48, c2 = e - (e/48)*48;
    int y = p/SX, xx = p - (p/SX)*SX;
    int gy = gy0+y, gx = gx0+xx;
    u32 v = 0;
    if (gy >= 0 && gy < 224 && gx >= 0 && gx < 224)
      v = *(const u32*)(src + ((size_t)((b*224+gy)*224+gx))*96 + c2*2);
    intile[p*49 + c2] = v;
  }
  const int pxg = tid & 31, og = tid >> 5;
  const int px8 = pxg & 15, py8 = pxg >> 4;
  const int o0 = og*12;
  float acc[4][12];
  #pragma unroll
  for (int a = 0; a < 4; a++)
    #pragma unroll
    for (int j = 0; j < 12; j++) acc[a][j] = 0.f;

  for (int ky = 0; ky < 3; ky++)
  for (int kx = 0; kx < 3; kx++){
    const int tap = ky*3+kx;
    __syncthreads();
    for (int e = tid; e < 4608; e += 256){
      int c = e/48, o2 = e - (e/48)*48;
      float wa = wOIHW[((2*o2)*96 + c)*9 + tap];
      float wb = wOIHW[((2*o2+1)*96 + c)*9 + tap];
      wsl[e] = pack2(wa, wb);
    }
    __syncthreads();
    for (int c2 = 0; c2 < 48; c2++){
      u32 iv[4];
      #pragma unroll
      for (int a = 0; a < 4; a++)
        iv[a] = intile[((py8+2*a+ky*DIL)*SX + (px8+kx*DIL))*49 + c2];
      const u32* wr0 = &wsl[(2*c2)*48 + og*6];
      const u32* wr1 = &wsl[(2*c2+1)*48 + og*6];
      float w0[12], w1f[12];
      #pragma unroll
      for (int d = 0; d < 6; d++){
        w0[2*d]=lo16(wr0[d]);  w0[2*d+1]=hi16(wr0[d]);
        w1f[2*d]=lo16(wr1[d]); w1f[2*d+1]=hi16(wr1[d]);
      }
      #pragma unroll
      for (int a = 0; a < 4; a++){
        float i0 = lo16(iv[a]), i1 = hi16(iv[a]);
        #pragma unroll
        for (int j = 0; j < 12; j++) acc[a][j] += i0*w0[j] + i1*w1f[j];
      }
    }
  }
  float sc[12], mm[12], bb[12], cbv[12];
  #pragma unroll
  for (int j = 0; j < 12; j++){
    sc[j] = bng[o0+j]*rsqrtf(bnv[o0+j]+1e-5f);
    mm[j] = bnm[o0+j]; bb[j] = bnb[o0+j]; cbv[j] = cb[o0+j];
  }
  #pragma unroll
  for (int a = 0; a < 4; a++){
    int gy = by + py8 + 2*a, gx = bx + px8;
    size_t base = ((size_t)((b*224+gy)*224+gx))*96 + o0;
    float4 r0 = *(const float4*)(resid + base);
    float4 r1 = *(const float4*)(resid + base + 4);
    float4 r2 = *(const float4*)(resid + base + 8);
    float ov[12];
    #pragma unroll
    for (int j = 0; j < 12; j++){
      float t = (acc[a][j] + cbv[j] - mm[j])*sc[j] + bb[j];
      ov[j] = gelu(t);
    }
    float4 s0, s1, s2;
    s0.x = ov[0]+r0.x;  s0.y = ov[1]+r0.y;  s0.z = ov[2]+r0.z;  s0.w = ov[3]+r0.w;
    s1.x = ov[4]+r1.x;  s1.y = ov[5]+r1.y;  s1.z = ov[6]+r1.z;  s1.w = ov[7]+r1.w;
    s2.x = ov[8]+r2.x;  s2.y = ov[9]+r2.y;  s2.z = ov[10]+r2.z; s2.w = ov[11]+r2.w;
    *(float4*)(dst + base)     = s0;
    *(float4*)(dst + base + 4) = s1;
    *(float4*)(dst + base + 8) = s2;
  }
}

// ---------------------------------------------------------------------------
extern "C" void kernel_launch(void* const* d_in, const int* in_sizes, int n_in,
                              void* d_out, int out_size, void* d_ws, size_t ws_size,
                              hipStream_t stream)
{
  const float* x    = (const float*)d_in[0];
  const float* ndwi = (const float*)d_in[1];
  const float* n1g  = (const float*)d_in[2];
  const float* n1b  = (const float*)d_in[3];
  const float* qkvw = (const float*)d_in[4];
  const float* qkvb = (const float*)d_in[5];
  const float* projw= (const float*)d_in[6];
  const float* projb= (const float*)d_in[7];
  const float* rpbt = (const float*)d_in[8];
  const float* n2g  = (const float*)d_in[9];
  const float* n2b  = (const float*)d_in[10];
  const float* w1   = (const float*)d_in[11];
  const float* b1   = (const float*)d_in[12];
  const float* w2   = (const float*)d_in[13];
  const float* b2   = (const float*)d_in[14];
  const float* n3g  = (const float*)d_in[15];
  const float* n3b  = (const float*)d_in[16];
  const float* c1w  = (const float*)d_in[17];
  const float* c1b  = (const float*)d_in[18];
  const float* bn1g = (const float*)d_in[19];
  const float* bn1b = (const float*)d_in[20];
  const float* bn1m = (const float*)d_in[21];
  const float* bn1v = (const float*)d_in[22];
  const float* c2w  = (const float*)d_in[23];
  const float* c2b  = (const float*)d_in[24];
  const float* bn2g = (const float*)d_in[25];
  const float* bn2b = (const float*)d_in[26];
  const float* bn2m = (const float*)d_in[27];
  const float* bn2v = (const float*)d_in[28];

  int B = out_size / (224*224*96);
  if (B < 1 || B > 64) B = 4;

  u16*   wsA = (u16*)d_ws;
  u16*   qwT = (u16*)d_out;
  u16*   pwT = qwT + 27648;
  float* xo  = (float*)d_out;

  wprep_k<<<dim3(144), dim3(256), 0, stream>>>(qkvw, projw, qwT, pwT);
  attn_k<<<dim3(B*1024), dim3(256), 0, stream>>>(x, ndwi, n1g, n1b, qwT, qkvb, pwT, projb, rpbt, wsA);
  mlp_k<<<dim3(B*784), dim3(256), 0, stream>>>(wsA, w1, b1, w2, b2, n2g, n2b, xo);
  conv1_k<<<dim3(14,28,B), dim3(256), 0, stream>>>(xo, c1w, c1b, bn1g, bn1b, bn1m, bn1v, n3g, n3b, wsA);
  conv2_k<<<dim3(14,28,B), dim3(256), 0, stream>>>(wsA, c2w, c2b, bn2g, bn2b, bn2m, bn2v, xo, xo);
}

// Round 8
// 2501.752 us; speedup vs baseline: 1.4861x; 1.2573x over previous
//
#include <hip/hip_runtime.h>
#include <hip/hip_bf16.h>

typedef unsigned int u32;
typedef unsigned short u16;

#define DF __device__ __forceinline__

DF float bf2f(u16 v){ u32 t = ((u32)v)<<16; return __builtin_bit_cast(float, t); }
DF u16 f2bf(float f){
  u32 t = __builtin_bit_cast(u32, f);
  t += 0x7fffu + ((t>>16)&1u);
  return (u16)(t>>16);
}
DF float lo16(u32 p){ return __builtin_bit_cast(float, p<<16); }
DF float hi16(u32 p){ return __builtin_bit_cast(float, p & 0xffff0000u); }
DF u32 pack2(float a, float b){ return (u32)f2bf(a) | (((u32)f2bf(b))<<16); }
DF float gelu(float x){ return 0.5f*x*(1.0f+erff(x*0.70710678118654752f)); }

// dot2: acc += a.lo*b.lo + a.hi*b.hi  (bf16 pairs, f32 accumulate)
#if defined(__has_builtin)
#if __has_builtin(__builtin_amdgcn_fdot2_f32_bf16)
#define HAVE_DOT2 1
#endif
#endif
#ifdef HAVE_DOT2
DF float dot2bf(u32 a, u32 b, float c){
  typedef __bf16 b2 __attribute__((ext_vector_type(2)));
  return __builtin_amdgcn_fdot2_f32_bf16(__builtin_bit_cast(b2,a), __builtin_bit_cast(b2,b), c, false);
}
#else
DF float dot2bf(u32 a, u32 b, float c){ return c + lo16(a)*lo16(b) + hi16(a)*hi16(b); }
#endif

// ---------------------------------------------------------------------------
// K0: pack qkv/proj weights for dot2: w8q[og(36)][cp(48)][k(8)] u32, each u32
// = bf16 pair (w[o][2cp], w[o][2cp+1]) with o = og*8+k.  w8p likewise (12 og).
// Staged in FRONT of d_out (consumed by attn before mlp overwrites).
// ---------------------------------------------------------------------------
__global__ void wprep_k(const float* __restrict__ qkvw, const float* __restrict__ projw,
                        u32* __restrict__ w8q, u32* __restrict__ w8p)
{
  int e = blockIdx.x*256 + threadIdx.x;
  if (e < 13824){
    int og = e/384, r = e - og*384, cp = r>>3, k = r&7;
    int o = og*8 + k;
    w8q[e] = pack2(qkvw[o*96 + 2*cp], qkvw[o*96 + 2*cp + 1]);
  } else if (e < 18432){
    int r2 = e - 13824;
    int og = r2/384, r = r2 - og*384, cp = r>>3, k = r&7;
    int o = og*8 + k;
    w8p[r2] = pack2(projw[o*96 + 2*cp], projw[o*96 + 2*cp + 1]);
  }
}

// ---------------------------------------------------------------------------
// K1: fused windowed attention, dot2 edition. One block (4 waves) per window.
// LDS 61.6KB -> 2 blocks/CU.
// ---------------------------------------------------------------------------
__global__ __launch_bounds__(256,2) void attn_k(
    const float* __restrict__ x, const float* __restrict__ ndwi,
    const float* __restrict__ n1g, const float* __restrict__ n1b,
    const u32* __restrict__ w8q, const float* __restrict__ qb,
    const u32* __restrict__ w8p, const float* __restrict__ pb,
    const float* __restrict__ rpbt, u16* __restrict__ x1o)
{
  __shared__ float xw[49*97];   // raw window f32; later proj result f32
  __shared__ u32 xp[49*49];     // LN'd x bf16 pairs [t][cp]; later attn-out pairs
  __shared__ u32 qp[49*49];     // q bf16 pairs along d, [t][o/2]
  __shared__ u32 kp[49*49];     // k bf16 pairs along d
  __shared__ u16 vpT[96*50];    // v transposed [d(96)][j], stride 50
  __shared__ float rpb[8*169];  // [h][idx]
  __shared__ float mw[49];
  const int tid = threadIdx.x;
  const int blk = blockIdx.x;
  const int b = blk >> 10, wy = (blk>>5)&31, wx = blk&31;
  const int wv_ = __builtin_amdgcn_readfirstlane(tid >> 6);
  const int ln  = tid & 63;
  const int lnc = ln < 49 ? ln : 48;

  for (int i = tid; i < 1352; i += 256){
    int h = i/169, idx = i - h*169;
    rpb[i] = rpbt[idx*8 + h];
  }
  for (int i = tid; i < 96; i += 256) vpT[i*50 + 49] = 0;  // pad elem (PV reads pairs)

  // gather shifted window (roll +3) + NDWI
  for (int e = tid; e < 49*48; e += 256){
    int t = e/48, c2 = e%48;
    int ty = t/7, tx = t%7;
    int sy = wy*7 + ty - 3; if (sy < 0) sy += 224;
    int sx = wx*7 + tx - 3; if (sx < 0) sx += 224;
    size_t base = ((size_t)((b*224 + sy)*224 + sx))*96;
    float2 p = *(const float2*)(x + base + c2*2);
    xw[t*97 + c2*2]   = p.x;
    xw[t*97 + c2*2+1] = p.y;
    if (c2 == 0) mw[t] = ndwi[(size_t)b*50176 + sy*224 + sx];
  }
  __syncthreads();

  // LN1: 4 lanes per token; write bf16 pairs to xp
  if (tid < 196){
    const int t = tid >> 2, p = tid & 3;
    float c[24];
    #pragma unroll
    for (int j = 0; j < 24; j++) c[j] = xw[t*97 + p*24 + j];
    float s = 0.f, s2 = 0.f;
    #pragma unroll
    for (int j = 0; j < 24; j++){ s += c[j]; s2 += c[j]*c[j]; }
    s  += __shfl_xor(s, 1);  s  += __shfl_xor(s, 2);
    s2 += __shfl_xor(s2, 1); s2 += __shfl_xor(s2, 2);
    float m = s*(1.f/96.f);
    float rs = rsqrtf(s2*(1.f/96.f) - m*m + 1e-5f);
    #pragma unroll
    for (int jj = 0; jj < 12; jj++){
      float a = (c[2*jj]  -m)*rs*n1g[p*24+2*jj]   + n1b[p*24+2*jj];
      float d = (c[2*jj+1]-m)*rs*n1g[p*24+2*jj+1] + n1b[p*24+2*jj+1];
      xp[t*49 + p*12 + jj] = pack2(a, d);
    }
  }
  __syncthreads();

  // QKV: wave handles 9 output-groups of 8; lane = token; dot2 inner loop
  for (int ogi = 0; ogi < 9; ogi++){
    const int og = wv_*9 + ogi;
    const int o0 = og*8;
    const u32* wrow = w8q + og*384;
    float acc[8];
    #pragma unroll
    for (int k = 0; k < 8; k++) acc[k] = qb[o0+k];
    #pragma unroll 4
    for (int cp = 0; cp < 48; cp++){
      u32 xv = xp[lnc*49 + cp];
      uint4 wa = *(const uint4*)(wrow + cp*8);
      uint4 wb = *(const uint4*)(wrow + cp*8 + 4);
      acc[0] = dot2bf(xv, wa.x, acc[0]); acc[1] = dot2bf(xv, wa.y, acc[1]);
      acc[2] = dot2bf(xv, wa.z, acc[2]); acc[3] = dot2bf(xv, wa.w, acc[3]);
      acc[4] = dot2bf(xv, wb.x, acc[4]); acc[5] = dot2bf(xv, wb.y, acc[5]);
      acc[6] = dot2bf(xv, wb.z, acc[6]); acc[7] = dot2bf(xv, wb.w, acc[7]);
    }
    if (ln < 49){
      if (og < 12){
        const float S = 0.28867513459481287f;   // 12^-0.5
        #pragma unroll
        for (int m = 0; m < 4; m++) qp[ln*49 + og*4 + m] = pack2(acc[2*m]*S, acc[2*m+1]*S);
      } else if (og < 24){
        #pragma unroll
        for (int m = 0; m < 4; m++) kp[ln*49 + (og-12)*4 + m] = pack2(acc[2*m], acc[2*m+1]);
      } else {
        const int o0v = (og-24)*8;
        #pragma unroll
        for (int k = 0; k < 8; k++) vpT[(o0v+k)*50 + ln] = f2bf(acc[k]);
      }
    }
  }
  __syncthreads();

  // attention: task = (head, query row); QK + PV via dot2
  for (int task = tid; task < 392; task += 256){
    int h = task/49, i = task - (task/49)*49;
    int iy = i/7, ix = i - (i/7)*7;
    u32 qv[6];
    #pragma unroll
    for (int e = 0; e < 6; e++) qv[e] = qp[i*49 + h*6 + e];
    const float* rb = &rpb[h*169 + (iy+6)*13 + (ix+6)];
    float s[49]; float mx = -1e30f;
    float mi = mw[i];
    int j = 0;
    #pragma unroll
    for (int jy = 0; jy < 7; jy++)
    #pragma unroll
    for (int jx = 0; jx < 7; jx++, j++){
      const u32* kr = &kp[j*49 + h*6];
      float a = rb[-(jy*13+jx)];
      a = dot2bf(qv[0], kr[0], a); a = dot2bf(qv[1], kr[1], a);
      a = dot2bf(qv[2], kr[2], a); a = dot2bf(qv[3], kr[3], a);
      a = dot2bf(qv[4], kr[4], a); a = dot2bf(qv[5], kr[5], a);
      a = (mi != mw[j]) ? a - 100.f : a;
      s[j] = a; mx = fmaxf(mx, a);
    }
    float l = 0.f;
    #pragma unroll
    for (int jj = 0; jj < 49; jj++){ float p = __expf(s[jj]-mx); s[jj] = p; l += p; }
    float rl = 1.f/l;
    // pack p (truncate to bf16; p>=0, tiny relative error)
    u32 pp[25];
    #pragma unroll
    for (int e = 0; e < 24; e++)
      pp[e] = (__builtin_bit_cast(u32, s[2*e]) >> 16)
            | (__builtin_bit_cast(u32, s[2*e+1]) & 0xffff0000u);
    pp[24] = __builtin_bit_cast(u32, s[48]) >> 16;
    float o[12];
    #pragma unroll
    for (int d = 0; d < 12; d++){
      const u32* vr = (const u32*)(vpT + (h*12+d)*50);
      float od = 0.f;
      #pragma unroll
      for (int e = 0; e < 25; e++) od = dot2bf(pp[e], vr[e], od);
      o[d] = od*rl;
    }
    #pragma unroll
    for (int m = 0; m < 6; m++) xp[i*49 + h*6 + m] = pack2(o[2*m], o[2*m+1]);
  }
  __syncthreads();

  // proj: wave handles 3 output-groups of 8; lane = token; result f32 -> xw
  for (int ogi = 0; ogi < 3; ogi++){
    const int og = wv_*3 + ogi;
    const int o0 = og*8;
    const u32* wrow = w8p + og*384;
    float acc[8];
    #pragma unroll
    for (int k = 0; k < 8; k++) acc[k] = pb[o0+k];
    #pragma unroll 4
    for (int cp = 0; cp < 48; cp++){
      u32 xv = xp[lnc*49 + cp];
      uint4 wa = *(const uint4*)(wrow + cp*8);
      uint4 wb = *(const uint4*)(wrow + cp*8 + 4);
      acc[0] = dot2bf(xv, wa.x, acc[0]); acc[1] = dot2bf(xv, wa.y, acc[1]);
      acc[2] = dot2bf(xv, wa.z, acc[2]); acc[3] = dot2bf(xv, wa.w, acc[3]);
      acc[4] = dot2bf(xv, wb.x, acc[4]); acc[5] = dot2bf(xv, wb.y, acc[5]);
      acc[6] = dot2bf(xv, wb.z, acc[6]); acc[7] = dot2bf(xv, wb.w, acc[7]);
    }
    if (ln < 49){
      #pragma unroll
      for (int k = 0; k < 8; k++) xw[ln*97 + o0 + k] = acc[k];
    }
  }
  __syncthreads();

  // write: reverse roll (-4) + residual; per-token contiguous uint4 runs
  for (int e = tid; e < 588; e += 256){
    int t = e/12, q4 = e - (e/12)*12;
    int ty = t/7, tx = t - (t/7)*7;
    int dy = wy*7 + ty - 4; if (dy < 0) dy += 224;
    int dx = wx*7 + tx - 4; if (dx < 0) dx += 224;
    size_t base = ((size_t)((b*224+dy)*224+dx))*96 + q4*8;
    float4 r0 = *(const float4*)(x + base);
    float4 r1 = *(const float4*)(x + base + 4);
    const float* orow = &xw[t*97 + q4*8];
    uint4 ov;
    ov.x = pack2(orow[0]+r0.x, orow[1]+r0.y);
    ov.y = pack2(orow[2]+r0.z, orow[3]+r0.w);
    ov.z = pack2(orow[4]+r1.x, orow[5]+r1.y);
    ov.w = pack2(orow[6]+r1.z, orow[7]+r1.w);
    *(uint4*)(x1o + base) = ov;
  }
}

// ---------------------------------------------------------------------------
// K2: fused LN2 + MLP (96->384 GELU ->96) + residual. x1(ws,bf16) -> x2(d_out,f32).
// Block-cooperative, 64 tokens/block. (unchanged from R7 — no longer hot)
// ---------------------------------------------------------------------------
__global__ __launch_bounds__(256,2) void mlp_k(
    const u16* __restrict__ x1, const float* __restrict__ w1, const float* __restrict__ b1,
    const float* __restrict__ w2, const float* __restrict__ b2,
    const float* __restrict__ g2, const float* __restrict__ bb2,
    float* __restrict__ x2o)
{
  __shared__ u32 xt[64*49];
  __shared__ u32 w1l[96*49];
  __shared__ u32 w2l[96*49];
  __shared__ u32 hl[64*49];
  __shared__ float b1s[384];
  const int tid = threadIdx.x;
  const size_t t0 = (size_t)blockIdx.x * 64;

  for (int i = tid; i < 384; i += 256) b1s[i] = b1[i];

  {
    const int t = tid >> 2, p = tid & 3;
    const u16* xr = x1 + (t0 + t)*96 + p*24;
    float c[24];
    #pragma unroll
    for (int q = 0; q < 3; q++){
      uint4 v = ((const uint4*)xr)[q];
      c[q*8+0]=lo16(v.x); c[q*8+1]=hi16(v.x);
      c[q*8+2]=lo16(v.y); c[q*8+3]=hi16(v.y);
      c[q*8+4]=lo16(v.z); c[q*8+5]=hi16(v.z);
      c[q*8+6]=lo16(v.w); c[q*8+7]=hi16(v.w);
    }
    float s = 0.f, s2 = 0.f;
    #pragma unroll
    for (int j = 0; j < 24; j++){ s += c[j]; s2 += c[j]*c[j]; }
    s  += __shfl_xor(s, 1);  s  += __shfl_xor(s, 2);
    s2 += __shfl_xor(s2, 1); s2 += __shfl_xor(s2, 2);
    float m = s*(1.f/96.f);
    float rs = rsqrtf(s2*(1.f/96.f) - m*m + 1e-5f);
    #pragma unroll
    for (int jj = 0; jj < 12; jj++){
      float a = (c[2*jj]  -m)*rs*g2[p*24+2*jj]   + bb2[p*24+2*jj];
      float d = (c[2*jj+1]-m)*rs*g2[p*24+2*jj+1] + bb2[p*24+2*jj+1];
      xt[t*49 + p*12 + jj] = pack2(a, d);
    }
  }

  const int ttg = tid & 15;
  const int hg  = tid >> 4;
  float oacc[4][6];
  #pragma unroll
  for (int i = 0; i < 4; i++)
    #pragma unroll
    for (int k = 0; k < 6; k++) oacc[i][k] = 0.f;

  for (int q = 0; q < 4; q++){
    const int h0 = q*96;
    __syncthreads();
    for (int e = tid; e < 4608; e += 256){
      int r = e/48, cpp = e - (e/48)*48;
      float2 a1 = *(const float2*)(w1 + (size_t)(h0+r)*96 + 2*cpp);
      w1l[r*49+cpp] = pack2(a1.x, a1.y);
      float2 a2 = *(const float2*)(w2 + (size_t)r*384 + h0 + 2*cpp);
      w2l[r*49+cpp] = pack2(a2.x, a2.y);
    }
    __syncthreads();
    float a[4][6];
    #pragma unroll
    for (int i = 0; i < 4; i++)
      #pragma unroll
      for (int k = 0; k < 6; k++) a[i][k] = b1s[h0 + hg*6 + k];
    for (int cp = 0; cp < 48; cp++){
      u32 xv[4], wv[6];
      #pragma unroll
      for (int i = 0; i < 4; i++) xv[i] = xt[(ttg*4+i)*49 + cp];
      #pragma unroll
      for (int k = 0; k < 6; k++) wv[k] = w1l[(hg*6+k)*49 + cp];
      #pragma unroll
      for (int i = 0; i < 4; i++)
        #pragma unroll
        for (int k = 0; k < 6; k++) a[i][k] = dot2bf(xv[i], wv[k], a[i][k]);
    }
    #pragma unroll
    for (int i = 0; i < 4; i++)
      #pragma unroll
      for (int p3 = 0; p3 < 3; p3++)
        hl[(ttg*4+i)*49 + hg*3 + p3] = pack2(gelu(a[i][2*p3]), gelu(a[i][2*p3+1]));
    __syncthreads();
    for (int hp = 0; hp < 48; hp++){
      u32 hv[4], wv[6];
      #pragma unroll
      for (int i = 0; i < 4; i++) hv[i] = hl[(ttg*4+i)*49 + hp];
      #pragma unroll
      for (int k = 0; k < 6; k++) wv[k] = w2l[(hg*6+k)*49 + hp];
      #pragma unroll
      for (int i = 0; i < 4; i++)
        #pragma unroll
        for (int k = 0; k < 6; k++) oacc[i][k] = dot2bf(hv[i], wv[k], oacc[i][k]);
    }
  }

  const int oc0 = hg*6;
  float b2v[6];
  #pragma unroll
  for (int k = 0; k < 6; k++) b2v[k] = b2[oc0+k];
  #pragma unroll
  for (int i = 0; i < 4; i++){
    size_t tok = t0 + ttg*4 + i;
    const u32* rr = (const u32*)(x1 + tok*96 + oc0);
    float* orow = x2o + tok*96 + oc0;
    #pragma unroll
    for (int p3 = 0; p3 < 3; p3++){
      u32 rv = rr[p3];
      float2 st;
      st.x = lo16(rv) + oacc[i][2*p3]   + b2v[2*p3];
      st.y = hi16(rv) + oacc[i][2*p3+1] + b2v[2*p3+1];
      *(float2*)(orow + 2*p3) = st;
    }
  }
}

// ---------------------------------------------------------------------------
// K3a: per-pixel LN3 + 3x3 conv (dil 1) + bias + BN + GELU. x2(f32)->h1(bf16).
// ---------------------------------------------------------------------------
__global__ __launch_bounds__(256,2) void conv1_k(
    const float* __restrict__ src, const float* __restrict__ wOIHW,
    const float* __restrict__ cb, const float* __restrict__ bng, const float* __restrict__ bnb,
    const float* __restrict__ bnm, const float* __restrict__ bnv,
    const float* __restrict__ g3, const float* __restrict__ b3,
    u16* __restrict__ dst)
{
  constexpr int DIL = 1, SY = 10, SX = 18;
  __shared__ u32 intile[SY*SX*49];
  __shared__ u32 wsl[4608];
  const int tid = threadIdx.x;
  const int bx = blockIdx.x*16, by = blockIdx.y*8, b = blockIdx.z;
  const int gy0 = by - DIL, gx0 = bx - DIL;
  for (int e = tid; e < SY*SX*48; e += 256){
    int p = e/48, c2 = e - (e/48)*48;
    int y = p/SX, xx = p - (p/SX)*SX;
    int gy = gy0+y, gx = gx0+xx;
    u32 v = 0;
    if (gy >= 0 && gy < 224 && gx >= 0 && gx < 224){
      float2 rd = *(const float2*)(src + ((size_t)((b*224+gy)*224+gx))*96 + c2*2);
      v = pack2(rd.x, rd.y);
    }
    intile[p*49 + c2] = v;
  }
  __syncthreads();
  for (int p = tid; p < SY*SX; p += 256){
    int y = p/SX, xx = p - (p/SX)*SX;
    int gy = gy0+y, gx = gx0+xx;
    if (gy >= 0 && gy < 224 && gx >= 0 && gx < 224){
      u32* row = &intile[p*49];
      float m = 0.f;
      #pragma unroll
      for (int c2 = 0; c2 < 48; c2++){ u32 v = row[c2]; m += lo16(v)+hi16(v); }
      m *= (1.f/96.f);
      float var = 0.f;
      #pragma unroll
      for (int c2 = 0; c2 < 48; c2++){
        u32 v = row[c2];
        float d0 = lo16(v)-m, d1 = hi16(v)-m;
        var += d0*d0 + d1*d1;
      }
      float rs = rsqrtf(var*(1.f/96.f)+1e-5f);
      #pragma unroll
      for (int c2 = 0; c2 < 48; c2++){
        u32 v = row[c2];
        float2 gg = *(const float2*)(g3 + 2*c2);
        float2 bb = *(const float2*)(b3 + 2*c2);
        row[c2] = pack2((lo16(v)-m)*rs*gg.x+bb.x,
                        (hi16(v)-m)*rs*gg.y+bb.y);
      }
    }
  }
  const int pxg = tid & 31, og = tid >> 5;
  const int px8 = pxg & 15, py8 = pxg >> 4;
  const int o0 = og*12;
  float acc[4][12];
  #pragma unroll
  for (int a = 0; a < 4; a++)
    #pragma unroll
    for (int j = 0; j < 12; j++) acc[a][j] = 0.f;

  for (int ky = 0; ky < 3; ky++)
  for (int kx = 0; kx < 3; kx++){
    const int tap = ky*3+kx;
    __syncthreads();
    for (int e = tid; e < 4608; e += 256){
      int c = e/48, o2 = e - (e/48)*48;
      float wa = wOIHW[((2*o2)*96 + c)*9 + tap];
      float wb = wOIHW[((2*o2+1)*96 + c)*9 + tap];
      wsl[e] = pack2(wa, wb);
    }
    __syncthreads();
    for (int c2 = 0; c2 < 48; c2++){
      u32 iv[4];
      #pragma unroll
      for (int a = 0; a < 4; a++)
        iv[a] = intile[((py8+2*a+ky*DIL)*SX + (px8+kx*DIL))*49 + c2];
      const u32* wr0 = &wsl[(2*c2)*48 + og*6];
      const u32* wr1 = &wsl[(2*c2+1)*48 + og*6];
      float w0[12], w1f[12];
      #pragma unroll
      for (int d = 0; d < 6; d++){
        w0[2*d]=lo16(wr0[d]);  w0[2*d+1]=hi16(wr0[d]);
        w1f[2*d]=lo16(wr1[d]); w1f[2*d+1]=hi16(wr1[d]);
      }
      #pragma unroll
      for (int a = 0; a < 4; a++){
        float i0 = lo16(iv[a]), i1 = hi16(iv[a]);
        #pragma unroll
        for (int j = 0; j < 12; j++) acc[a][j] += i0*w0[j] + i1*w1f[j];
      }
    }
  }
  float sc[12], mm[12], bb[12], cbv[12];
  #pragma unroll
  for (int j = 0; j < 12; j++){
    sc[j] = bng[o0+j]*rsqrtf(bnv[o0+j]+1e-5f);
    mm[j] = bnm[o0+j]; bb[j] = bnb[o0+j]; cbv[j] = cb[o0+j];
  }
  #pragma unroll
  for (int a = 0; a < 4; a++){
    int gy = by + py8 + 2*a, gx = bx + px8;
    size_t base = ((size_t)((b*224+gy)*224+gx))*96 + o0;
    #pragma unroll
    for (int d = 0; d < 6; d++){
      float t0 = (acc[a][2*d]   + cbv[2*d]   - mm[2*d])  *sc[2*d]   + bb[2*d];
      float t1 = (acc[a][2*d+1] + cbv[2*d+1] - mm[2*d+1])*sc[2*d+1] + bb[2*d+1];
      *(u32*)(dst + base + 2*d) = pack2(gelu(t0), gelu(t1));
    }
  }
}

// ---------------------------------------------------------------------------
// K3b: 3x3 conv (dil 2) + bias + BN + GELU + residual(x2) -> final f32.
// ---------------------------------------------------------------------------
__global__ __launch_bounds__(256,2) void conv2_k(
    const u16* __restrict__ src, const float* __restrict__ wOIHW,
    const float* __restrict__ cb, const float* __restrict__ bng, const float* __restrict__ bnb,
    const float* __restrict__ bnm, const float* __restrict__ bnv,
    const float* resid, float* dst)
{
  constexpr int DIL = 2, SY = 12, SX = 20;
  __shared__ u32 intile[SY*SX*49];
  __shared__ u32 wsl[4608];
  const int tid = threadIdx.x;
  const int bx = blockIdx.x*16, by = blockIdx.y*8, b = blockIdx.z;
  const int gy0 = by - DIL, gx0 = bx - DIL;
  for (int e = tid; e < SY*SX*48; e += 256){
    int p = e/48, c2 = e - (e/48)*48;
    int y = p/SX, xx = p - (p/SX)*SX;
    int gy = gy0+y, gx = gx0+xx;
    u32 v = 0;
    if (gy >= 0 && gy < 224 && gx >= 0 && gx < 224)
      v = *(const u32*)(src + ((size_t)((b*224+gy)*224+gx))*96 + c2*2);
    intile[p*49 + c2] = v;
  }
  const int pxg = tid & 31, og = tid >> 5;
  const int px8 = pxg & 15, py8 = pxg >> 4;
  const int o0 = og*12;
  float acc[4][12];
  #pragma unroll
  for (int a = 0; a < 4; a++)
    #pragma unroll
    for (int j = 0; j < 12; j++) acc[a][j] = 0.f;

  for (int ky = 0; ky < 3; ky++)
  for (int kx = 0; kx < 3; kx++){
    const int tap = ky*3+kx;
    __syncthreads();
    for (int e = tid; e < 4608; e += 256){
      int c = e/48, o2 = e - (e/48)*48;
      float wa = wOIHW[((2*o2)*96 + c)*9 + tap];
      float wb = wOIHW[((2*o2+1)*96 + c)*9 + tap];
      wsl[e] = pack2(wa, wb);
    }
    __syncthreads();
    for (int c2 = 0; c2 < 48; c2++){
      u32 iv[4];
      #pragma unroll
      for (int a = 0; a < 4; a++)
        iv[a] = intile[((py8+2*a+ky*DIL)*SX + (px8+kx*DIL))*49 + c2];
      const u32* wr0 = &wsl[(2*c2)*48 + og*6];
      const u32* wr1 = &wsl[(2*c2+1)*48 + og*6];
      float w0[12], w1f[12];
      #pragma unroll
      for (int d = 0; d < 6; d++){
        w0[2*d]=lo16(wr0[d]);  w0[2*d+1]=hi16(wr0[d]);
        w1f[2*d]=lo16(wr1[d]); w1f[2*d+1]=hi16(wr1[d]);
      }
      #pragma unroll
      for (int a = 0; a < 4; a++){
        float i0 = lo16(iv[a]), i1 = hi16(iv[a]);
        #pragma unroll
        for (int j = 0; j < 12; j++) acc[a][j] += i0*w0[j] + i1*w1f[j];
      }
    }
  }
  float sc[12], mm[12], bb[12], cbv[12];
  #pragma unroll
  for (int j = 0; j < 12; j++){
    sc[j] = bng[o0+j]*rsqrtf(bnv[o0+j]+1e-5f);
    mm[j] = bnm[o0+j]; bb[j] = bnb[o0+j]; cbv[j] = cb[o0+j];
  }
  #pragma unroll
  for (int a = 0; a < 4; a++){
    int gy = by + py8 + 2*a, gx = bx + px8;
    size_t base = ((size_t)((b*224+gy)*224+gx))*96 + o0;
    float4 r0 = *(const float4*)(resid + base);
    float4 r1 = *(const float4*)(resid + base + 4);
    float4 r2 = *(const float4*)(resid + base + 8);
    float ov[12];
    #pragma unroll
    for (int j = 0; j < 12; j++){
      float t = (acc[a][j] + cbv[j] - mm[j])*sc[j] + bb[j];
      ov[j] = gelu(t);
    }
    float4 s0, s1, s2;
    s0.x = ov[0]+r0.x;  s0.y = ov[1]+r0.y;  s0.z = ov[2]+r0.z;  s0.w = ov[3]+r0.w;
    s1.x = ov[4]+r1.x;  s1.y = ov[5]+r1.y;  s1.z = ov[6]+r1.z;  s1.w = ov[7]+r1.w;
    s2.x = ov[8]+r2.x;  s2.y = ov[9]+r2.y;  s2.z = ov[10]+r2.z; s2.w = ov[11]+r2.w;
    *(float4*)(dst + base)     = s0;
    *(float4*)(dst + base + 4) = s1;
    *(float4*)(dst + base + 8) = s2;
  }
}

// ---------------------------------------------------------------------------
extern "C" void kernel_launch(void* const* d_in, const int* in_sizes, int n_in,
                              void* d_out, int out_size, void* d_ws, size_t ws_size,
                              hipStream_t stream)
{
  const float* x    = (const float*)d_in[0];
  const float* ndwi = (const float*)d_in[1];
  const float* n1g  = (const float*)d_in[2];
  const float* n1b  = (const float*)d_in[3];
  const float* qkvw = (const float*)d_in[4];
  const float* qkvb = (const float*)d_in[5];
  const float* projw= (const float*)d_in[6];
  const float* projb= (const float*)d_in[7];
  const float* rpbt = (const float*)d_in[8];
  const float* n2g  = (const float*)d_in[9];
  const float* n2b  = (const float*)d_in[10];
  const float* w1   = (const float*)d_in[11];
  const float* b1   = (const float*)d_in[12];
  const float* w2   = (const float*)d_in[13];
  const float* b2   = (const float*)d_in[14];
  const float* n3g  = (const float*)d_in[15];
  const float* n3b  = (const float*)d_in[16];
  const float* c1w  = (const float*)d_in[17];
  const float* c1b  = (const float*)d_in[18];
  const float* bn1g = (const float*)d_in[19];
  const float* bn1b = (const float*)d_in[20];
  const float* bn1m = (const float*)d_in[21];
  const float* bn1v = (const float*)d_in[22];
  const float* c2w  = (const float*)d_in[23];
  const float* c2b  = (const float*)d_in[24];
  const float* bn2g = (const float*)d_in[25];
  const float* bn2b = (const float*)d_in[26];
  const float* bn2m = (const float*)d_in[27];
  const float* bn2v = (const float*)d_in[28];

  int B = out_size / (224*224*96);
  if (B < 1 || B > 64) B = 4;

  // d_out (f32): [w8q|w8p u32 staging 73.7KB] -> x2 (f32) -> final
  // d_ws  (bf16): x1 (attn out) -> h1 (conv1 out)
  u16*   wsA = (u16*)d_ws;
  u32*   w8q = (u32*)d_out;
  u32*   w8p = w8q + 13824;
  float* xo  = (float*)d_out;

  wprep_k<<<dim3(72), dim3(256), 0, stream>>>(qkvw, projw, w8q, w8p);
  attn_k<<<dim3(B*1024), dim3(256), 0, stream>>>(x, ndwi, n1g, n1b, w8q, qkvb, w8p, projb, rpbt, wsA);
  mlp_k<<<dim3(B*784), dim3(256), 0, stream>>>(wsA, w1, b1, w2, b2, n2g, n2b, xo);
  conv1_k<<<dim3(14,28,B), dim3(256), 0, stream>>>(xo, c1w, c1b, bn1g, bn1b, bn1m, bn1v, n3g, n3b, wsA);
  conv2_k<<<dim3(14,28,B), dim3(256), 0, stream>>>(wsA, c2w, c2b, bn2g, bn2b, bn2m, bn2v, xo, xo);
}

// Round 9
// 1617.678 us; speedup vs baseline: 2.2983x; 1.5465x over previous
//
#include <hip/hip_runtime.h>
#include <hip/hip_bf16.h>

typedef unsigned int u32;
typedef unsigned short u16;

#define DF __device__ __forceinline__

DF float bf2f(u16 v){ u32 t = ((u32)v)<<16; return __builtin_bit_cast(float, t); }
DF u16 f2bf(float f){
  u32 t = __builtin_bit_cast(u32, f);
  t += 0x7fffu + ((t>>16)&1u);
  return (u16)(t>>16);
}
DF float lo16(u32 p){ return __builtin_bit_cast(float, p<<16); }
DF float hi16(u32 p){ return __builtin_bit_cast(float, p & 0xffff0000u); }
DF u32 pack2(float a, float b){ return (u32)f2bf(a) | (((u32)f2bf(b))<<16); }
DF float gelu(float x){ return 0.5f*x*(1.0f+erff(x*0.70710678118654752f)); }

#if defined(__has_builtin)
#if __has_builtin(__builtin_amdgcn_fdot2_f32_bf16)
#define HAVE_DOT2 1
#endif
#endif
#ifdef HAVE_DOT2
DF float dot2bf(u32 a, u32 b, float c){
  typedef __bf16 b2 __attribute__((ext_vector_type(2)));
  return __builtin_amdgcn_fdot2_f32_bf16(__builtin_bit_cast(b2,a), __builtin_bit_cast(b2,b), c, false);
}
#else
DF float dot2bf(u32 a, u32 b, float c){ return c + lo16(a)*lo16(b) + hi16(a)*hi16(b); }
#endif

// ---------------------------------------------------------------------------
// K0: pack qkv/proj weights for dot2 (front of d_out, consumed by attn).
// ---------------------------------------------------------------------------
__global__ void wprep_k(const float* __restrict__ qkvw, const float* __restrict__ projw,
                        u32* __restrict__ w8q, u32* __restrict__ w8p)
{
  int e = blockIdx.x*256 + threadIdx.x;
  if (e < 13824){
    int og = e/384, r = e - og*384, cp = r>>3, k = r&7;
    int o = og*8 + k;
    w8q[e] = pack2(qkvw[o*96 + 2*cp], qkvw[o*96 + 2*cp + 1]);
  } else if (e < 18432){
    int r2 = e - 13824;
    int og = r2/384, r = r2 - og*384, cp = r>>3, k = r&7;
    int o = og*8 + k;
    w8p[r2] = pack2(projw[o*96 + 2*cp], projw[o*96 + 2*cp + 1]);
  }
}

// ---------------------------------------------------------------------------
// K0b: pack conv weights for dot2 into ws tail: [conv][tap][c2(48)][o(96)]
// each u32 = (w[o][2c2][tap], w[o][2c2+1][tap]) bf16 pair.
// ---------------------------------------------------------------------------
__global__ void wprep_cv(const float* __restrict__ c1w, const float* __restrict__ c2w,
                         u32* __restrict__ wcv)
{
  int e = blockIdx.x*256 + threadIdx.x;
  if (e >= 82944) return;
  int conv = e / 41472, r = e - conv*41472;
  int tap = r / 4608, r2 = r - tap*4608;
  int c2 = r2 / 96, o = r2 - c2*96;
  const float* s = conv ? c2w : c1w;
  wcv[e] = pack2(s[(o*96 + 2*c2)*9 + tap], s[(o*96 + 2*c2 + 1)*9 + tap]);
}

// ---------------------------------------------------------------------------
// K1: fused windowed attention, dot2 edition (unchanged from R8).
// ---------------------------------------------------------------------------
__global__ __launch_bounds__(256,2) void attn_k(
    const float* __restrict__ x, const float* __restrict__ ndwi,
    const float* __restrict__ n1g, const float* __restrict__ n1b,
    const u32* __restrict__ w8q, const float* __restrict__ qb,
    const u32* __restrict__ w8p, const float* __restrict__ pb,
    const float* __restrict__ rpbt, u16* __restrict__ x1o)
{
  __shared__ float xw[49*97];
  __shared__ u32 xp[49*49];
  __shared__ u32 qp[49*49];
  __shared__ u32 kp[49*49];
  __shared__ u16 vpT[96*50];
  __shared__ float rpb[8*169];
  __shared__ float mw[49];
  const int tid = threadIdx.x;
  const int blk = blockIdx.x;
  const int b = blk >> 10, wy = (blk>>5)&31, wx = blk&31;
  const int wv_ = __builtin_amdgcn_readfirstlane(tid >> 6);
  const int ln  = tid & 63;
  const int lnc = ln < 49 ? ln : 48;

  for (int i = tid; i < 1352; i += 256){
    int h = i/169, idx = i - h*169;
    rpb[i] = rpbt[idx*8 + h];
  }
  for (int i = tid; i < 96; i += 256) vpT[i*50 + 49] = 0;

  for (int e = tid; e < 49*48; e += 256){
    int t = e/48, c2 = e%48;
    int ty = t/7, tx = t%7;
    int sy = wy*7 + ty - 3; if (sy < 0) sy += 224;
    int sx = wx*7 + tx - 3; if (sx < 0) sx += 224;
    size_t base = ((size_t)((b*224 + sy)*224 + sx))*96;
    float2 p = *(const float2*)(x + base + c2*2);
    xw[t*97 + c2*2]   = p.x;
    xw[t*97 + c2*2+1] = p.y;
    if (c2 == 0) mw[t] = ndwi[(size_t)b*50176 + sy*224 + sx];
  }
  __syncthreads();

  if (tid < 196){
    const int t = tid >> 2, p = tid & 3;
    float c[24];
    #pragma unroll
    for (int j = 0; j < 24; j++) c[j] = xw[t*97 + p*24 + j];
    float s = 0.f, s2 = 0.f;
    #pragma unroll
    for (int j = 0; j < 24; j++){ s += c[j]; s2 += c[j]*c[j]; }
    s  += __shfl_xor(s, 1);  s  += __shfl_xor(s, 2);
    s2 += __shfl_xor(s2, 1); s2 += __shfl_xor(s2, 2);
    float m = s*(1.f/96.f);
    float rs = rsqrtf(s2*(1.f/96.f) - m*m + 1e-5f);
    #pragma unroll
    for (int jj = 0; jj < 12; jj++){
      float a = (c[2*jj]  -m)*rs*n1g[p*24+2*jj]   + n1b[p*24+2*jj];
      float d = (c[2*jj+1]-m)*rs*n1g[p*24+2*jj+1] + n1b[p*24+2*jj+1];
      xp[t*49 + p*12 + jj] = pack2(a, d);
    }
  }
  __syncthreads();

  for (int ogi = 0; ogi < 9; ogi++){
    const int og = wv_*9 + ogi;
    const int o0 = og*8;
    const u32* wrow = w8q + og*384;
    float acc[8];
    #pragma unroll
    for (int k = 0; k < 8; k++) acc[k] = qb[o0+k];
    #pragma unroll 4
    for (int cp = 0; cp < 48; cp++){
      u32 xv = xp[lnc*49 + cp];
      uint4 wa = *(const uint4*)(wrow + cp*8);
      uint4 wb = *(const uint4*)(wrow + cp*8 + 4);
      acc[0] = dot2bf(xv, wa.x, acc[0]); acc[1] = dot2bf(xv, wa.y, acc[1]);
      acc[2] = dot2bf(xv, wa.z, acc[2]); acc[3] = dot2bf(xv, wa.w, acc[3]);
      acc[4] = dot2bf(xv, wb.x, acc[4]); acc[5] = dot2bf(xv, wb.y, acc[5]);
      acc[6] = dot2bf(xv, wb.z, acc[6]); acc[7] = dot2bf(xv, wb.w, acc[7]);
    }
    if (ln < 49){
      if (og < 12){
        const float S = 0.28867513459481287f;
        #pragma unroll
        for (int m = 0; m < 4; m++) qp[ln*49 + og*4 + m] = pack2(acc[2*m]*S, acc[2*m+1]*S);
      } else if (og < 24){
        #pragma unroll
        for (int m = 0; m < 4; m++) kp[ln*49 + (og-12)*4 + m] = pack2(acc[2*m], acc[2*m+1]);
      } else {
        const int o0v = (og-24)*8;
        #pragma unroll
        for (int k = 0; k < 8; k++) vpT[(o0v+k)*50 + ln] = f2bf(acc[k]);
      }
    }
  }
  __syncthreads();

  for (int task = tid; task < 392; task += 256){
    int h = task/49, i = task - (task/49)*49;
    int iy = i/7, ix = i - (i/7)*7;
    u32 qv[6];
    #pragma unroll
    for (int e = 0; e < 6; e++) qv[e] = qp[i*49 + h*6 + e];
    const float* rb = &rpb[h*169 + (iy+6)*13 + (ix+6)];
    float s[49]; float mx = -1e30f;
    float mi = mw[i];
    int j = 0;
    #pragma unroll
    for (int jy = 0; jy < 7; jy++)
    #pragma unroll
    for (int jx = 0; jx < 7; jx++, j++){
      const u32* kr = &kp[j*49 + h*6];
      float a = rb[-(jy*13+jx)];
      a = dot2bf(qv[0], kr[0], a); a = dot2bf(qv[1], kr[1], a);
      a = dot2bf(qv[2], kr[2], a); a = dot2bf(qv[3], kr[3], a);
      a = dot2bf(qv[4], kr[4], a); a = dot2bf(qv[5], kr[5], a);
      a = (mi != mw[j]) ? a - 100.f : a;
      s[j] = a; mx = fmaxf(mx, a);
    }
    float l = 0.f;
    #pragma unroll
    for (int jj = 0; jj < 49; jj++){ float p = __expf(s[jj]-mx); s[jj] = p; l += p; }
    float rl = 1.f/l;
    u32 pp[25];
    #pragma unroll
    for (int e = 0; e < 24; e++)
      pp[e] = (__builtin_bit_cast(u32, s[2*e]) >> 16)
            | (__builtin_bit_cast(u32, s[2*e+1]) & 0xffff0000u);
    pp[24] = __builtin_bit_cast(u32, s[48]) >> 16;
    float o[12];
    #pragma unroll
    for (int d = 0; d < 12; d++){
      const u32* vr = (const u32*)(vpT + (h*12+d)*50);
      float od = 0.f;
      #pragma unroll
      for (int e = 0; e < 25; e++) od = dot2bf(pp[e], vr[e], od);
      o[d] = od*rl;
    }
    #pragma unroll
    for (int m = 0; m < 6; m++) xp[i*49 + h*6 + m] = pack2(o[2*m], o[2*m+1]);
  }
  __syncthreads();

  for (int ogi = 0; ogi < 3; ogi++){
    const int og = wv_*3 + ogi;
    const int o0 = og*8;
    const u32* wrow = w8p + og*384;
    float acc[8];
    #pragma unroll
    for (int k = 0; k < 8; k++) acc[k] = pb[o0+k];
    #pragma unroll 4
    for (int cp = 0; cp < 48; cp++){
      u32 xv = xp[lnc*49 + cp];
      uint4 wa = *(const uint4*)(wrow + cp*8);
      uint4 wb = *(const uint4*)(wrow + cp*8 + 4);
      acc[0] = dot2bf(xv, wa.x, acc[0]); acc[1] = dot2bf(xv, wa.y, acc[1]);
      acc[2] = dot2bf(xv, wa.z, acc[2]); acc[3] = dot2bf(xv, wa.w, acc[3]);
      acc[4] = dot2bf(xv, wb.x, acc[4]); acc[5] = dot2bf(xv, wb.y, acc[5]);
      acc[6] = dot2bf(xv, wb.z, acc[6]); acc[7] = dot2bf(xv, wb.w, acc[7]);
    }
    if (ln < 49){
      #pragma unroll
      for (int k = 0; k < 8; k++) xw[ln*97 + o0 + k] = acc[k];
    }
  }
  __syncthreads();

  for (int e = tid; e < 588; e += 256){
    int t = e/12, q4 = e - (e/12)*12;
    int ty = t/7, tx = t - (t/7)*7;
    int dy = wy*7 + ty - 4; if (dy < 0) dy += 224;
    int dx = wx*7 + tx - 4; if (dx < 0) dx += 224;
    size_t base = ((size_t)((b*224+dy)*224+dx))*96 + q4*8;
    float4 r0 = *(const float4*)(x + base);
    float4 r1 = *(const float4*)(x + base + 4);
    const float* orow = &xw[t*97 + q4*8];
    uint4 ov;
    ov.x = pack2(orow[0]+r0.x, orow[1]+r0.y);
    ov.y = pack2(orow[2]+r0.z, orow[3]+r0.w);
    ov.z = pack2(orow[4]+r1.x, orow[5]+r1.y);
    ov.w = pack2(orow[6]+r1.z, orow[7]+r1.w);
    *(uint4*)(x1o + base) = ov;
  }
}

// ---------------------------------------------------------------------------
// K2: fused LN2 + MLP + residual (unchanged from R8).
// ---------------------------------------------------------------------------
__global__ __launch_bounds__(256,2) void mlp_k(
    const u16* __restrict__ x1, const float* __restrict__ w1, const float* __restrict__ b1,
    const float* __restrict__ w2, const float* __restrict__ b2,
    const float* __restrict__ g2, const float* __restrict__ bb2,
    float* __restrict__ x2o)
{
  __shared__ u32 xt[64*49];
  __shared__ u32 w1l[96*49];
  __shared__ u32 w2l[96*49];
  __shared__ u32 hl[64*49];
  __shared__ float b1s[384];
  const int tid = threadIdx.x;
  const size_t t0 = (size_t)blockIdx.x * 64;

  for (int i = tid; i < 384; i += 256) b1s[i] = b1[i];

  {
    const int t = tid >> 2, p = tid & 3;
    const u16* xr = x1 + (t0 + t)*96 + p*24;
    float c[24];
    #pragma unroll
    for (int q = 0; q < 3; q++){
      uint4 v = ((const uint4*)xr)[q];
      c[q*8+0]=lo16(v.x); c[q*8+1]=hi16(v.x);
      c[q*8+2]=lo16(v.y); c[q*8+3]=hi16(v.y);
      c[q*8+4]=lo16(v.z); c[q*8+5]=hi16(v.z);
      c[q*8+6]=lo16(v.w); c[q*8+7]=hi16(v.w);
    }
    float s = 0.f, s2 = 0.f;
    #pragma unroll
    for (int j = 0; j < 24; j++){ s += c[j]; s2 += c[j]*c[j]; }
    s  += __shfl_xor(s, 1);  s  += __shfl_xor(s, 2);
    s2 += __shfl_xor(s2, 1); s2 += __shfl_xor(s2, 2);
    float m = s*(1.f/96.f);
    float rs = rsqrtf(s2*(1.f/96.f) - m*m + 1e-5f);
    #pragma unroll
    for (int jj = 0; jj < 12; jj++){
      float a = (c[2*jj]  -m)*rs*g2[p*24+2*jj]   + bb2[p*24+2*jj];
      float d = (c[2*jj+1]-m)*rs*g2[p*24+2*jj+1] + bb2[p*24+2*jj+1];
      xt[t*49 + p*12 + jj] = pack2(a, d);
    }
  }

  const int ttg = tid & 15;
  const int hg  = tid >> 4;
  float oacc[4][6];
  #pragma unroll
  for (int i = 0; i < 4; i++)
    #pragma unroll
    for (int k = 0; k < 6; k++) oacc[i][k] = 0.f;

  for (int q = 0; q < 4; q++){
    const int h0 = q*96;
    __syncthreads();
    for (int e = tid; e < 4608; e += 256){
      int r = e/48, cpp = e - (e/48)*48;
      float2 a1 = *(const float2*)(w1 + (size_t)(h0+r)*96 + 2*cpp);
      w1l[r*49+cpp] = pack2(a1.x, a1.y);
      float2 a2 = *(const float2*)(w2 + (size_t)r*384 + h0 + 2*cpp);
      w2l[r*49+cpp] = pack2(a2.x, a2.y);
    }
    __syncthreads();
    float a[4][6];
    #pragma unroll
    for (int i = 0; i < 4; i++)
      #pragma unroll
      for (int k = 0; k < 6; k++) a[i][k] = b1s[h0 + hg*6 + k];
    for (int cp = 0; cp < 48; cp++){
      u32 xv[4], wv[6];
      #pragma unroll
      for (int i = 0; i < 4; i++) xv[i] = xt[(ttg*4+i)*49 + cp];
      #pragma unroll
      for (int k = 0; k < 6; k++) wv[k] = w1l[(hg*6+k)*49 + cp];
      #pragma unroll
      for (int i = 0; i < 4; i++)
        #pragma unroll
        for (int k = 0; k < 6; k++) a[i][k] = dot2bf(xv[i], wv[k], a[i][k]);
    }
    #pragma unroll
    for (int i = 0; i < 4; i++)
      #pragma unroll
      for (int p3 = 0; p3 < 3; p3++)
        hl[(ttg*4+i)*49 + hg*3 + p3] = pack2(gelu(a[i][2*p3]), gelu(a[i][2*p3+1]));
    __syncthreads();
    for (int hp = 0; hp < 48; hp++){
      u32 hv[4], wv[6];
      #pragma unroll
      for (int i = 0; i < 4; i++) hv[i] = hl[(ttg*4+i)*49 + hp];
      #pragma unroll
      for (int k = 0; k < 6; k++) wv[k] = w2l[(hg*6+k)*49 + hp];
      #pragma unroll
      for (int i = 0; i < 4; i++)
        #pragma unroll
        for (int k = 0; k < 6; k++) oacc[i][k] = dot2bf(hv[i], wv[k], oacc[i][k]);
    }
  }

  const int oc0 = hg*6;
  float b2v[6];
  #pragma unroll
  for (int k = 0; k < 6; k++) b2v[k] = b2[oc0+k];
  #pragma unroll
  for (int i = 0; i < 4; i++){
    size_t tok = t0 + ttg*4 + i;
    const u32* rr = (const u32*)(x1 + tok*96 + oc0);
    float* orow = x2o + tok*96 + oc0;
    #pragma unroll
    for (int p3 = 0; p3 < 3; p3++){
      u32 rv = rr[p3];
      float2 st;
      st.x = lo16(rv) + oacc[i][2*p3]   + b2v[2*p3];
      st.y = hi16(rv) + oacc[i][2*p3+1] + b2v[2*p3+1];
      *(float2*)(orow + 2*p3) = st;
    }
  }
}

// ---------------------------------------------------------------------------
// K3a: per-pixel LN3 + 3x3 conv (dil 1) + bias + BN + GELU, dot2 edition.
// Weights from packed wpk (or in-kernel gather fallback if wpk==nullptr).
// ---------------------------------------------------------------------------
__global__ __launch_bounds__(256,2) void conv1_k(
    const float* __restrict__ src, const u32* __restrict__ wpk,
    const float* __restrict__ wOIHW,
    const float* __restrict__ cb, const float* __restrict__ bng, const float* __restrict__ bnb,
    const float* __restrict__ bnm, const float* __restrict__ bnv,
    const float* __restrict__ g3, const float* __restrict__ b3,
    u16* __restrict__ dst)
{
  constexpr int DIL = 1, SY = 10, SX = 18;
  __shared__ u32 intile[SY*SX*49];
  __shared__ __align__(16) u32 wsl[4608];   // [c2(48)][o(96)] bf16 pairs
  const int tid = threadIdx.x;
  const int bx = blockIdx.x*16, by = blockIdx.y*8, b = blockIdx.z;
  const int gy0 = by - DIL, gx0 = bx - DIL;
  for (int e = tid; e < SY*SX*48; e += 256){
    int p = e/48, c2 = e - (e/48)*48;
    int y = p/SX, xx = p - (p/SX)*SX;
    int gy = gy0+y, gx = gx0+xx;
    u32 v = 0;
    if (gy >= 0 && gy < 224 && gx >= 0 && gx < 224){
      float2 rd = *(const float2*)(src + ((size_t)((b*224+gy)*224+gx))*96 + c2*2);
      v = pack2(rd.x, rd.y);
    }
    intile[p*49 + c2] = v;
  }
  __syncthreads();
  for (int p = tid; p < SY*SX; p += 256){
    int y = p/SX, xx = p - (p/SX)*SX;
    int gy = gy0+y, gx = gx0+xx;
    if (gy >= 0 && gy < 224 && gx >= 0 && gx < 224){
      u32* row = &intile[p*49];
      float m = 0.f;
      #pragma unroll
      for (int c2 = 0; c2 < 48; c2++){ u32 v = row[c2]; m += lo16(v)+hi16(v); }
      m *= (1.f/96.f);
      float var = 0.f;
      #pragma unroll
      for (int c2 = 0; c2 < 48; c2++){
        u32 v = row[c2];
        float d0 = lo16(v)-m, d1 = hi16(v)-m;
        var += d0*d0 + d1*d1;
      }
      float rs = rsqrtf(var*(1.f/96.f)+1e-5f);
      #pragma unroll
      for (int c2 = 0; c2 < 48; c2++){
        u32 v = row[c2];
        float2 gg = *(const float2*)(g3 + 2*c2);
        float2 bb = *(const float2*)(b3 + 2*c2);
        row[c2] = pack2((lo16(v)-m)*rs*gg.x+bb.x,
                        (hi16(v)-m)*rs*gg.y+bb.y);
      }
    }
  }
  const int pxg = tid & 31, og = tid >> 5;
  const int px8 = pxg & 15, py8 = pxg >> 4;
  const int o0 = og*12;
  float acc[4][12];
  #pragma unroll
  for (int a = 0; a < 4; a++)
    #pragma unroll
    for (int j = 0; j < 12; j++) acc[a][j] = 0.f;

  for (int tap = 0; tap < 9; tap++){
    const int ky = tap/3, kx = tap - (tap/3)*3;
    __syncthreads();
    if (wpk){
      const u32* wsrc = wpk + tap*4608;
      for (int e = tid; e < 4608; e += 256) wsl[e] = wsrc[e];
    } else {
      for (int e = tid; e < 4608; e += 256){
        int c2 = e/96, o = e - (e/96)*96;
        wsl[e] = pack2(wOIHW[(o*96 + 2*c2)*9 + tap], wOIHW[(o*96 + 2*c2 + 1)*9 + tap]);
      }
    }
    __syncthreads();
    for (int c2 = 0; c2 < 48; c2++){
      u32 iv[4];
      #pragma unroll
      for (int a = 0; a < 4; a++)
        iv[a] = intile[((py8+2*a+ky*DIL)*SX + (px8+kx*DIL))*49 + c2];
      const u32* wr = &wsl[c2*96 + o0];
      uint4 wA = *(const uint4*)(wr);
      uint4 wB = *(const uint4*)(wr+4);
      uint4 wC = *(const uint4*)(wr+8);
      #pragma unroll
      for (int a = 0; a < 4; a++){
        u32 v = iv[a];
        acc[a][0]  = dot2bf(v, wA.x, acc[a][0]);
        acc[a][1]  = dot2bf(v, wA.y, acc[a][1]);
        acc[a][2]  = dot2bf(v, wA.z, acc[a][2]);
        acc[a][3]  = dot2bf(v, wA.w, acc[a][3]);
        acc[a][4]  = dot2bf(v, wB.x, acc[a][4]);
        acc[a][5]  = dot2bf(v, wB.y, acc[a][5]);
        acc[a][6]  = dot2bf(v, wB.z, acc[a][6]);
        acc[a][7]  = dot2bf(v, wB.w, acc[a][7]);
        acc[a][8]  = dot2bf(v, wC.x, acc[a][8]);
        acc[a][9]  = dot2bf(v, wC.y, acc[a][9]);
        acc[a][10] = dot2bf(v, wC.z, acc[a][10]);
        acc[a][11] = dot2bf(v, wC.w, acc[a][11]);
      }
    }
  }
  float sc[12], mm[12], bb[12], cbv[12];
  #pragma unroll
  for (int j = 0; j < 12; j++){
    sc[j] = bng[o0+j]*rsqrtf(bnv[o0+j]+1e-5f);
    mm[j] = bnm[o0+j]; bb[j] = bnb[o0+j]; cbv[j] = cb[o0+j];
  }
  #pragma unroll
  for (int a = 0; a < 4; a++){
    int gy = by + py8 + 2*a, gx = bx + px8;
    size_t base = ((size_t)((b*224+gy)*224+gx))*96 + o0;
    #pragma unroll
    for (int d = 0; d < 6; d++){
      float t0 = (acc[a][2*d]   + cbv[2*d]   - mm[2*d])  *sc[2*d]   + bb[2*d];
      float t1 = (acc[a][2*d+1] + cbv[2*d+1] - mm[2*d+1])*sc[2*d+1] + bb[2*d+1];
      *(u32*)(dst + base + 2*d) = pack2(gelu(t0), gelu(t1));
    }
  }
}

// ---------------------------------------------------------------------------
// K3b: 3x3 conv (dil 2) + bias + BN + GELU + residual(x2), dot2 edition.
// ---------------------------------------------------------------------------
__global__ __launch_bounds__(256,2) void conv2_k(
    const u16* __restrict__ src, const u32* __restrict__ wpk,
    const float* __restrict__ wOIHW,
    const float* __restrict__ cb, const float* __restrict__ bng, const float* __restrict__ bnb,
    const float* __restrict__ bnm, const float* __restrict__ bnv,
    const float* resid, float* dst)
{
  constexpr int DIL = 2, SY = 12, SX = 20;
  __shared__ u32 intile[SY*SX*49];
  __shared__ __align__(16) u32 wsl[4608];
  const int tid = threadIdx.x;
  const int bx = blockIdx.x*16, by = blockIdx.y*8, b = blockIdx.z;
  const int gy0 = by - DIL, gx0 = bx - DIL;
  for (int e = tid; e < SY*SX*48; e += 256){
    int p = e/48, c2 = e - (e/48)*48;
    int y = p/SX, xx = p - (p/SX)*SX;
    int gy = gy0+y, gx = gx0+xx;
    u32 v = 0;
    if (gy >= 0 && gy < 224 && gx >= 0 && gx < 224)
      v = *(const u32*)(src + ((size_t)((b*224+gy)*224+gx))*96 + c2*2);
    intile[p*49 + c2] = v;
  }
  const int pxg = tid & 31, og = tid >> 5;
  const int px8 = pxg & 15, py8 = pxg >> 4;
  const int o0 = og*12;
  float acc[4][12];
  #pragma unroll
  for (int a = 0; a < 4; a++)
    #pragma unroll
    for (int j = 0; j < 12; j++) acc[a][j] = 0.f;

  for (int tap = 0; tap < 9; tap++){
    const int ky = tap/3, kx = tap - (tap/3)*3;
    __syncthreads();
    if (wpk){
      const u32* wsrc = wpk + tap*4608;
      for (int e = tid; e < 4608; e += 256) wsl[e] = wsrc[e];
    } else {
      for (int e = tid; e < 4608; e += 256){
        int c2 = e/96, o = e - (e/96)*96;
        wsl[e] = pack2(wOIHW[(o*96 + 2*c2)*9 + tap], wOIHW[(o*96 + 2*c2 + 1)*9 + tap]);
      }
    }
    __syncthreads();
    for (int c2 = 0; c2 < 48; c2++){
      u32 iv[4];
      #pragma unroll
      for (int a = 0; a < 4; a++)
        iv[a] = intile[((py8+2*a+ky*DIL)*SX + (px8+kx*DIL))*49 + c2];
      const u32* wr = &wsl[c2*96 + o0];
      uint4 wA = *(const uint4*)(wr);
      uint4 wB = *(const uint4*)(wr+4);
      uint4 wC = *(const uint4*)(wr+8);
      #pragma unroll
      for (int a = 0; a < 4; a++){
        u32 v = iv[a];
        acc[a][0]  = dot2bf(v, wA.x, acc[a][0]);
        acc[a][1]  = dot2bf(v, wA.y, acc[a][1]);
        acc[a][2]  = dot2bf(v, wA.z, acc[a][2]);
        acc[a][3]  = dot2bf(v, wA.w, acc[a][3]);
        acc[a][4]  = dot2bf(v, wB.x, acc[a][4]);
        acc[a][5]  = dot2bf(v, wB.y, acc[a][5]);
        acc[a][6]  = dot2bf(v, wB.z, acc[a][6]);
        acc[a][7]  = dot2bf(v, wB.w, acc[a][7]);
        acc[a][8]  = dot2bf(v, wC.x, acc[a][8]);
        acc[a][9]  = dot2bf(v, wC.y, acc[a][9]);
        acc[a][10] = dot2bf(v, wC.z, acc[a][10]);
        acc[a][11] = dot2bf(v, wC.w, acc[a][11]);
      }
    }
  }
  float sc[12], mm[12], bb[12], cbv[12];
  #pragma unroll
  for (int j = 0; j < 12; j++){
    sc[j] = bng[o0+j]*rsqrtf(bnv[o0+j]+1e-5f);
    mm[j] = bnm[o0+j]; bb[j] = bnb[o0+j]; cbv[j] = cb[o0+j];
  }
  #pragma unroll
  for (int a = 0; a < 4; a++){
    int gy = by + py8 + 2*a, gx = bx + px8;
    size_t base = ((size_t)((b*224+gy)*224+gx))*96 + o0;
    float4 r0 = *(const float4*)(resid + base);
    float4 r1 = *(const float4*)(resid + base + 4);
    float4 r2 = *(const float4*)(resid + base + 8);
    float ov[12];
    #pragma unroll
    for (int j = 0; j < 12; j++){
      float t = (acc[a][j] + cbv[j] - mm[j])*sc[j] + bb[j];
      ov[j] = gelu(t);
    }
    float4 s0, s1, s2;
    s0.x = ov[0]+r0.x;  s0.y = ov[1]+r0.y;  s0.z = ov[2]+r0.z;  s0.w = ov[3]+r0.w;
    s1.x = ov[4]+r1.x;  s1.y = ov[5]+r1.y;  s1.z = ov[6]+r1.z;  s1.w = ov[7]+r1.w;
    s2.x = ov[8]+r2.x;  s2.y = ov[9]+r2.y;  s2.z = ov[10]+r2.z; s2.w = ov[11]+r2.w;
    *(float4*)(dst + base)     = s0;
    *(float4*)(dst + base + 4) = s1;
    *(float4*)(dst + base + 8) = s2;
  }
}

// ---------------------------------------------------------------------------
extern "C" void kernel_launch(void* const* d_in, const int* in_sizes, int n_in,
                              void* d_out, int out_size, void* d_ws, size_t ws_size,
                              hipStream_t stream)
{
  const float* x    = (const float*)d_in[0];
  const float* ndwi = (const float*)d_in[1];
  const float* n1g  = (const float*)d_in[2];
  const float* n1b  = (const float*)d_in[3];
  const float* qkvw = (const float*)d_in[4];
  const float* qkvb = (const float*)d_in[5];
  const float* projw= (const float*)d_in[6];
  const float* projb= (const float*)d_in[7];
  const float* rpbt = (const float*)d_in[8];
  const float* n2g  = (const float*)d_in[9];
  const float* n2b  = (const float*)d_in[10];
  const float* w1   = (const float*)d_in[11];
  const float* b1   = (const float*)d_in[12];
  const float* w2   = (const float*)d_in[13];
  const float* b2   = (const float*)d_in[14];
  const float* n3g  = (const float*)d_in[15];
  const float* n3b  = (const float*)d_in[16];
  const float* c1w  = (const float*)d_in[17];
  const float* c1b  = (const float*)d_in[18];
  const float* bn1g = (const float*)d_in[19];
  const float* bn1b = (const float*)d_in[20];
  const float* bn1m = (const float*)d_in[21];
  const float* bn1v = (const float*)d_in[22];
  const float* c2w  = (const float*)d_in[23];
  const float* c2b  = (const float*)d_in[24];
  const float* bn2g = (const float*)d_in[25];
  const float* bn2b = (const float*)d_in[26];
  const float* bn2m = (const float*)d_in[27];
  const float* bn2v = (const float*)d_in[28];

  int B = out_size / (224*224*96);
  if (B < 1 || B > 64) B = 4;
  const size_t elems = (size_t)B*224*224*96;

  // d_out (f32): [w8q|w8p staging 73.7KB] -> x2 (f32) -> final
  // d_ws: x1/h1 bf16 (38.5MB) + packed conv weights (332KB, if room)
  u16*   wsA = (u16*)d_ws;
  u32*   w8q = (u32*)d_out;
  u32*   w8p = w8q + 13824;
  float* xo  = (float*)d_out;
  u32*   wcv = nullptr;
  if (ws_size >= elems*sizeof(u16) + 82944*sizeof(u32))
    wcv = (u32*)(wsA + elems);

  wprep_k<<<dim3(72), dim3(256), 0, stream>>>(qkvw, projw, w8q, w8p);
  if (wcv) wprep_cv<<<dim3(324), dim3(256), 0, stream>>>(c1w, c2w, wcv);
  attn_k<<<dim3(B*1024), dim3(256), 0, stream>>>(x, ndwi, n1g, n1b, w8q, qkvb, w8p, projb, rpbt, wsA);
  mlp_k<<<dim3(B*784), dim3(256), 0, stream>>>(wsA, w1, b1, w2, b2, n2g, n2b, xo);
  conv1_k<<<dim3(14,28,B), dim3(256), 0, stream>>>(xo, wcv, c1w, c1b, bn1g, bn1b, bn1m, bn1v, n3g, n3b, wsA);
  conv2_k<<<dim3(14,28,B), dim3(256), 0, stream>>>(wsA, wcv ? wcv + 41472 : nullptr, c2w, c2b, bn2g, bn2b, bn2m, bn2v, xo, xo);
}

// Round 10
// 1514.864 us; speedup vs baseline: 2.4543x; 1.0679x over previous
//
#include <hip/hip_runtime.h>
#include <hip/hip_bf16.h>

typedef unsigned int u32;
typedef unsigned short u16;

#define DF __device__ __forceinline__

DF float bf2f(u16 v){ u32 t = ((u32)v)<<16; return __builtin_bit_cast(float, t); }
DF u16 f2bf(float f){
  u32 t = __builtin_bit_cast(u32, f);
  t += 0x7fffu + ((t>>16)&1u);
  return (u16)(t>>16);
}
DF float lo16(u32 p){ return __builtin_bit_cast(float, p<<16); }
DF float hi16(u32 p){ return __builtin_bit_cast(float, p & 0xffff0000u); }
DF u32 pack2(float a, float b){ return (u32)f2bf(a) | (((u32)f2bf(b))<<16); }
DF float gelu(float x){ return 0.5f*x*(1.0f+erff(x*0.70710678118654752f)); }

#if defined(__has_builtin)
#if __has_builtin(__builtin_amdgcn_fdot2_f32_bf16)
#define HAVE_DOT2 1
#endif
#endif
#ifdef HAVE_DOT2
DF float dot2bf(u32 a, u32 b, float c){
  typedef __bf16 b2 __attribute__((ext_vector_type(2)));
  return __builtin_amdgcn_fdot2_f32_bf16(__builtin_bit_cast(b2,a), __builtin_bit_cast(b2,b), c, false);
}
#else
DF float dot2bf(u32 a, u32 b, float c){ return c + lo16(a)*lo16(b) + hi16(a)*hi16(b); }
#endif

// ---------------------------------------------------------------------------
// K0: pack qkv/proj weights for dot2 (front of d_out, consumed by attn).
// ---------------------------------------------------------------------------
__global__ void wprep_k(const float* __restrict__ qkvw, const float* __restrict__ projw,
                        u32* __restrict__ w8q, u32* __restrict__ w8p)
{
  int e = blockIdx.x*256 + threadIdx.x;
  if (e < 13824){
    int og = e/384, r = e - og*384, cp = r>>3, k = r&7;
    int o = og*8 + k;
    w8q[e] = pack2(qkvw[o*96 + 2*cp], qkvw[o*96 + 2*cp + 1]);
  } else if (e < 18432){
    int r2 = e - 13824;
    int og = r2/384, r = r2 - og*384, cp = r>>3, k = r&7;
    int o = og*8 + k;
    w8p[r2] = pack2(projw[o*96 + 2*cp], projw[o*96 + 2*cp + 1]);
  }
}

// ---------------------------------------------------------------------------
// K0b: pack conv weights for dot2 into ws tail: [conv][tap][c2(48)][o(96)].
// ---------------------------------------------------------------------------
__global__ void wprep_cv(const float* __restrict__ c1w, const float* __restrict__ c2w,
                         u32* __restrict__ wcv)
{
  int e = blockIdx.x*256 + threadIdx.x;
  if (e >= 82944) return;
  int conv = e / 41472, r = e - conv*41472;
  int tap = r / 4608, r2 = r - tap*4608;
  int c2 = r2 / 96, o = r2 - c2*96;
  const float* s = conv ? c2w : c1w;
  wcv[e] = pack2(s[(o*96 + 2*c2)*9 + tap], s[(o*96 + 2*c2 + 1)*9 + tap]);
}

// ---------------------------------------------------------------------------
// K1: fused windowed attention, 43KB-LDS edition -> 3 blocks/CU.
// LN1 reads global directly; proj-out stored bf16 in qp (dead after QK^T).
// ---------------------------------------------------------------------------
__global__ __launch_bounds__(256,3) void attn_k(
    const float* __restrict__ x, const float* __restrict__ ndwi,
    const float* __restrict__ n1g, const float* __restrict__ n1b,
    const u32* __restrict__ w8q, const float* __restrict__ qb,
    const u32* __restrict__ w8p, const float* __restrict__ pb,
    const float* __restrict__ rpbt, u16* __restrict__ x1o)
{
  __shared__ u32 xp[49*49];     // LN'd x bf16 pairs [t][cp]; later attn-out pairs
  __shared__ u32 qp[49*49];     // q bf16 pairs; later proj-out pairs
  __shared__ u32 kp[49*49];     // k bf16 pairs
  __shared__ u16 vpT[96*50];    // v transposed [d][j], stride 50
  __shared__ float rpb[8*169];  // [h][idx]
  __shared__ float mw[49];
  const int tid = threadIdx.x;
  const int blk = blockIdx.x;
  const int b = blk >> 10, wy = (blk>>5)&31, wx = blk&31;
  const int wv_ = __builtin_amdgcn_readfirstlane(tid >> 6);
  const int ln  = tid & 63;
  const int lnc = ln < 49 ? ln : 48;

  for (int i = tid; i < 1352; i += 256){
    int h = i/169, idx = i - h*169;
    rpb[i] = rpbt[idx*8 + h];
  }
  for (int i = tid; i < 96; i += 256) vpT[i*50 + 49] = 0;

  // LN1 straight from global: 4 lanes per token, 24 channels each.
  if (tid < 196){
    const int t = tid >> 2, p = tid & 3;
    const int ty = t/7, tx = t - (t/7)*7;
    int sy = wy*7 + ty - 3; if (sy < 0) sy += 224;
    int sx = wx*7 + tx - 3; if (sx < 0) sx += 224;
    const size_t rowb = ((size_t)((b*224 + sy)*224 + sx))*96;
    const float* xr = x + rowb + p*24;
    float c[24];
    #pragma unroll
    for (int q = 0; q < 6; q++){
      float4 v = ((const float4*)xr)[q];
      c[q*4+0]=v.x; c[q*4+1]=v.y; c[q*4+2]=v.z; c[q*4+3]=v.w;
    }
    if (p == 0) mw[t] = ndwi[(size_t)b*50176 + sy*224 + sx];
    float s = 0.f, s2 = 0.f;
    #pragma unroll
    for (int j = 0; j < 24; j++){ s += c[j]; s2 += c[j]*c[j]; }
    s  += __shfl_xor(s, 1);  s  += __shfl_xor(s, 2);
    s2 += __shfl_xor(s2, 1); s2 += __shfl_xor(s2, 2);
    float m = s*(1.f/96.f);
    float rs = rsqrtf(s2*(1.f/96.f) - m*m + 1e-5f);
    #pragma unroll
    for (int jj = 0; jj < 12; jj++){
      float a = (c[2*jj]  -m)*rs*n1g[p*24+2*jj]   + n1b[p*24+2*jj];
      float d = (c[2*jj+1]-m)*rs*n1g[p*24+2*jj+1] + n1b[p*24+2*jj+1];
      xp[t*49 + p*12 + jj] = pack2(a, d);
    }
  }
  __syncthreads();

  // QKV: wave handles 9 output-groups of 8; lane = token
  for (int ogi = 0; ogi < 9; ogi++){
    const int og = wv_*9 + ogi;
    const int o0 = og*8;
    const u32* wrow = w8q + og*384;
    float acc[8];
    #pragma unroll
    for (int k = 0; k < 8; k++) acc[k] = qb[o0+k];
    #pragma unroll 4
    for (int cp = 0; cp < 48; cp++){
      u32 xv = xp[lnc*49 + cp];
      uint4 wa = *(const uint4*)(wrow + cp*8);
      uint4 wb = *(const uint4*)(wrow + cp*8 + 4);
      acc[0] = dot2bf(xv, wa.x, acc[0]); acc[1] = dot2bf(xv, wa.y, acc[1]);
      acc[2] = dot2bf(xv, wa.z, acc[2]); acc[3] = dot2bf(xv, wa.w, acc[3]);
      acc[4] = dot2bf(xv, wb.x, acc[4]); acc[5] = dot2bf(xv, wb.y, acc[5]);
      acc[6] = dot2bf(xv, wb.z, acc[6]); acc[7] = dot2bf(xv, wb.w, acc[7]);
    }
    if (ln < 49){
      if (og < 12){
        const float S = 0.28867513459481287f;
        #pragma unroll
        for (int m = 0; m < 4; m++) qp[ln*49 + og*4 + m] = pack2(acc[2*m]*S, acc[2*m+1]*S);
      } else if (og < 24){
        #pragma unroll
        for (int m = 0; m < 4; m++) kp[ln*49 + (og-12)*4 + m] = pack2(acc[2*m], acc[2*m+1]);
      } else {
        const int o0v = (og-24)*8;
        #pragma unroll
        for (int k = 0; k < 8; k++) vpT[(o0v+k)*50 + ln] = f2bf(acc[k]);
      }
    }
  }
  __syncthreads();

  // attention: task = (head, query row); QK + PV via dot2; out -> xp
  for (int task = tid; task < 392; task += 256){
    int h = task/49, i = task - (task/49)*49;
    int iy = i/7, ix = i - (i/7)*7;
    u32 qv[6];
    #pragma unroll
    for (int e = 0; e < 6; e++) qv[e] = qp[i*49 + h*6 + e];
    const float* rb = &rpb[h*169 + (iy+6)*13 + (ix+6)];
    float s[49]; float mx = -1e30f;
    float mi = mw[i];
    int j = 0;
    #pragma unroll
    for (int jy = 0; jy < 7; jy++)
    #pragma unroll
    for (int jx = 0; jx < 7; jx++, j++){
      const u32* kr = &kp[j*49 + h*6];
      float a = rb[-(jy*13+jx)];
      a = dot2bf(qv[0], kr[0], a); a = dot2bf(qv[1], kr[1], a);
      a = dot2bf(qv[2], kr[2], a); a = dot2bf(qv[3], kr[3], a);
      a = dot2bf(qv[4], kr[4], a); a = dot2bf(qv[5], kr[5], a);
      a = (mi != mw[j]) ? a - 100.f : a;
      s[j] = a; mx = fmaxf(mx, a);
    }
    float l = 0.f;
    #pragma unroll
    for (int jj = 0; jj < 49; jj++){ float p = __expf(s[jj]-mx); s[jj] = p; l += p; }
    float rl = 1.f/l;
    u32 pp[25];
    #pragma unroll
    for (int e = 0; e < 24; e++)
      pp[e] = (__builtin_bit_cast(u32, s[2*e]) >> 16)
            | (__builtin_bit_cast(u32, s[2*e+1]) & 0xffff0000u);
    pp[24] = __builtin_bit_cast(u32, s[48]) >> 16;
    float o[12];
    #pragma unroll
    for (int d = 0; d < 12; d++){
      const u32* vr = (const u32*)(vpT + (h*12+d)*50);
      float od = 0.f;
      #pragma unroll
      for (int e = 0; e < 25; e++) od = dot2bf(pp[e], vr[e], od);
      o[d] = od*rl;
    }
    #pragma unroll
    for (int m = 0; m < 6; m++) xp[i*49 + h*6 + m] = pack2(o[2*m], o[2*m+1]);
  }
  __syncthreads();

  // proj: wave handles 3 output-groups of 8; result bf16 pairs -> qp (dead)
  for (int ogi = 0; ogi < 3; ogi++){
    const int og = wv_*3 + ogi;
    const int o0 = og*8;
    const u32* wrow = w8p + og*384;
    float acc[8];
    #pragma unroll
    for (int k = 0; k < 8; k++) acc[k] = pb[o0+k];
    #pragma unroll 4
    for (int cp = 0; cp < 48; cp++){
      u32 xv = xp[lnc*49 + cp];
      uint4 wa = *(const uint4*)(wrow + cp*8);
      uint4 wb = *(const uint4*)(wrow + cp*8 + 4);
      acc[0] = dot2bf(xv, wa.x, acc[0]); acc[1] = dot2bf(xv, wa.y, acc[1]);
      acc[2] = dot2bf(xv, wa.z, acc[2]); acc[3] = dot2bf(xv, wa.w, acc[3]);
      acc[4] = dot2bf(xv, wb.x, acc[4]); acc[5] = dot2bf(xv, wb.y, acc[5]);
      acc[6] = dot2bf(xv, wb.z, acc[6]); acc[7] = dot2bf(xv, wb.w, acc[7]);
    }
    if (ln < 49){
      #pragma unroll
      for (int m = 0; m < 4; m++) qp[ln*49 + og*4 + m] = pack2(acc[2*m], acc[2*m+1]);
    }
  }
  __syncthreads();

  // write: reverse roll (-4) + residual; per-token contiguous uint4 runs
  for (int e = tid; e < 588; e += 256){
    int t = e/12, g = e - (e/12)*12;
    int ty = t/7, tx = t - (t/7)*7;
    int dy = wy*7 + ty - 4; if (dy < 0) dy += 224;
    int dx = wx*7 + tx - 4; if (dx < 0) dx += 224;
    size_t base = ((size_t)((b*224+dy)*224+dx))*96 + g*8;
    float4 r0 = *(const float4*)(x + base);
    float4 r1 = *(const float4*)(x + base + 4);
    const u32* pr = &qp[t*49 + g*4];
    uint4 ov;
    ov.x = pack2(lo16(pr[0])+r0.x, hi16(pr[0])+r0.y);
    ov.y = pack2(lo16(pr[1])+r0.z, hi16(pr[1])+r0.w);
    ov.z = pack2(lo16(pr[2])+r1.x, hi16(pr[2])+r1.y);
    ov.w = pack2(lo16(pr[3])+r1.z, hi16(pr[3])+r1.w);
    *(uint4*)(x1o + base) = ov;
  }
}

// ---------------------------------------------------------------------------
// K2: fused LN2 + MLP + residual (unchanged).
// ---------------------------------------------------------------------------
__global__ __launch_bounds__(256,2) void mlp_k(
    const u16* __restrict__ x1, const float* __restrict__ w1, const float* __restrict__ b1,
    const float* __restrict__ w2, const float* __restrict__ b2,
    const float* __restrict__ g2, const float* __restrict__ bb2,
    float* __restrict__ x2o)
{
  __shared__ u32 xt[64*49];
  __shared__ u32 w1l[96*49];
  __shared__ u32 w2l[96*49];
  __shared__ u32 hl[64*49];
  __shared__ float b1s[384];
  const int tid = threadIdx.x;
  const size_t t0 = (size_t)blockIdx.x * 64;

  for (int i = tid; i < 384; i += 256) b1s[i] = b1[i];

  {
    const int t = tid >> 2, p = tid & 3;
    const u16* xr = x1 + (t0 + t)*96 + p*24;
    float c[24];
    #pragma unroll
    for (int q = 0; q < 3; q++){
      uint4 v = ((const uint4*)xr)[q];
      c[q*8+0]=lo16(v.x); c[q*8+1]=hi16(v.x);
      c[q*8+2]=lo16(v.y); c[q*8+3]=hi16(v.y);
      c[q*8+4]=lo16(v.z); c[q*8+5]=hi16(v.z);
      c[q*8+6]=lo16(v.w); c[q*8+7]=hi16(v.w);
    }
    float s = 0.f, s2 = 0.f;
    #pragma unroll
    for (int j = 0; j < 24; j++){ s += c[j]; s2 += c[j]*c[j]; }
    s  += __shfl_xor(s, 1);  s  += __shfl_xor(s, 2);
    s2 += __shfl_xor(s2, 1); s2 += __shfl_xor(s2, 2);
    float m = s*(1.f/96.f);
    float rs = rsqrtf(s2*(1.f/96.f) - m*m + 1e-5f);
    #pragma unroll
    for (int jj = 0; jj < 12; jj++){
      float a = (c[2*jj]  -m)*rs*g2[p*24+2*jj]   + bb2[p*24+2*jj];
      float d = (c[2*jj+1]-m)*rs*g2[p*24+2*jj+1] + bb2[p*24+2*jj+1];
      xt[t*49 + p*12 + jj] = pack2(a, d);
    }
  }

  const int ttg = tid & 15;
  const int hg  = tid >> 4;
  float oacc[4][6];
  #pragma unroll
  for (int i = 0; i < 4; i++)
    #pragma unroll
    for (int k = 0; k < 6; k++) oacc[i][k] = 0.f;

  for (int q = 0; q < 4; q++){
    const int h0 = q*96;
    __syncthreads();
    for (int e = tid; e < 4608; e += 256){
      int r = e/48, cpp = e - (e/48)*48;
      float2 a1 = *(const float2*)(w1 + (size_t)(h0+r)*96 + 2*cpp);
      w1l[r*49+cpp] = pack2(a1.x, a1.y);
      float2 a2 = *(const float2*)(w2 + (size_t)r*384 + h0 + 2*cpp);
      w2l[r*49+cpp] = pack2(a2.x, a2.y);
    }
    __syncthreads();
    float a[4][6];
    #pragma unroll
    for (int i = 0; i < 4; i++)
      #pragma unroll
      for (int k = 0; k < 6; k++) a[i][k] = b1s[h0 + hg*6 + k];
    for (int cp = 0; cp < 48; cp++){
      u32 xv[4], wv[6];
      #pragma unroll
      for (int i = 0; i < 4; i++) xv[i] = xt[(ttg*4+i)*49 + cp];
      #pragma unroll
      for (int k = 0; k < 6; k++) wv[k] = w1l[(hg*6+k)*49 + cp];
      #pragma unroll
      for (int i = 0; i < 4; i++)
        #pragma unroll
        for (int k = 0; k < 6; k++) a[i][k] = dot2bf(xv[i], wv[k], a[i][k]);
    }
    #pragma unroll
    for (int i = 0; i < 4; i++)
      #pragma unroll
      for (int p3 = 0; p3 < 3; p3++)
        hl[(ttg*4+i)*49 + hg*3 + p3] = pack2(gelu(a[i][2*p3]), gelu(a[i][2*p3+1]));
    __syncthreads();
    for (int hp = 0; hp < 48; hp++){
      u32 hv[4], wv[6];
      #pragma unroll
      for (int i = 0; i < 4; i++) hv[i] = hl[(ttg*4+i)*49 + hp];
      #pragma unroll
      for (int k = 0; k < 6; k++) wv[k] = w2l[(hg*6+k)*49 + hp];
      #pragma unroll
      for (int i = 0; i < 4; i++)
        #pragma unroll
        for (int k = 0; k < 6; k++) oacc[i][k] = dot2bf(hv[i], wv[k], oacc[i][k]);
    }
  }

  const int oc0 = hg*6;
  float b2v[6];
  #pragma unroll
  for (int k = 0; k < 6; k++) b2v[k] = b2[oc0+k];
  #pragma unroll
  for (int i = 0; i < 4; i++){
    size_t tok = t0 + ttg*4 + i;
    const u32* rr = (const u32*)(x1 + tok*96 + oc0);
    float* orow = x2o + tok*96 + oc0;
    #pragma unroll
    for (int p3 = 0; p3 < 3; p3++){
      u32 rv = rr[p3];
      float2 st;
      st.x = lo16(rv) + oacc[i][2*p3]   + b2v[2*p3];
      st.y = hi16(rv) + oacc[i][2*p3+1] + b2v[2*p3+1];
      *(float2*)(orow + 2*p3) = st;
    }
  }
}

// ---------------------------------------------------------------------------
// K3a: per-pixel LN3 + 3x3 conv (dil 1) + bias + BN + GELU, dot2 (unchanged).
// ---------------------------------------------------------------------------
__global__ __launch_bounds__(256,2) void conv1_k(
    const float* __restrict__ src, const u32* __restrict__ wpk,
    const float* __restrict__ wOIHW,
    const float* __restrict__ cb, const float* __restrict__ bng, const float* __restrict__ bnb,
    const float* __restrict__ bnm, const float* __restrict__ bnv,
    const float* __restrict__ g3, const float* __restrict__ b3,
    u16* __restrict__ dst)
{
  constexpr int DIL = 1, SY = 10, SX = 18;
  __shared__ u32 intile[SY*SX*49];
  __shared__ __align__(16) u32 wsl[4608];
  const int tid = threadIdx.x;
  const int bx = blockIdx.x*16, by = blockIdx.y*8, b = blockIdx.z;
  const int gy0 = by - DIL, gx0 = bx - DIL;
  for (int e = tid; e < SY*SX*48; e += 256){
    int p = e/48, c2 = e - (e/48)*48;
    int y = p/SX, xx = p - (p/SX)*SX;
    int gy = gy0+y, gx = gx0+xx;
    u32 v = 0;
    if (gy >= 0 && gy < 224 && gx >= 0 && gx < 224){
      float2 rd = *(const float2*)(src + ((size_t)((b*224+gy)*224+gx))*96 + c2*2);
      v = pack2(rd.x, rd.y);
    }
    intile[p*49 + c2] = v;
  }
  __syncthreads();
  for (int p = tid; p < SY*SX; p += 256){
    int y = p/SX, xx = p - (p/SX)*SX;
    int gy = gy0+y, gx = gx0+xx;
    if (gy >= 0 && gy < 224 && gx >= 0 && gx < 224){
      u32* row = &intile[p*49];
      float m = 0.f;
      #pragma unroll
      for (int c2 = 0; c2 < 48; c2++){ u32 v = row[c2]; m += lo16(v)+hi16(v); }
      m *= (1.f/96.f);
      float var = 0.f;
      #pragma unroll
      for (int c2 = 0; c2 < 48; c2++){
        u32 v = row[c2];
        float d0 = lo16(v)-m, d1 = hi16(v)-m;
        var += d0*d0 + d1*d1;
      }
      float rs = rsqrtf(var*(1.f/96.f)+1e-5f);
      #pragma unroll
      for (int c2 = 0; c2 < 48; c2++){
        u32 v = row[c2];
        float2 gg = *(const float2*)(g3 + 2*c2);
        float2 bb = *(const float2*)(b3 + 2*c2);
        row[c2] = pack2((lo16(v)-m)*rs*gg.x+bb.x,
                        (hi16(v)-m)*rs*gg.y+bb.y);
      }
    }
  }
  const int pxg = tid & 31, og = tid >> 5;
  const int px8 = pxg & 15, py8 = pxg >> 4;
  const int o0 = og*12;
  float acc[4][12];
  #pragma unroll
  for (int a = 0; a < 4; a++)
    #pragma unroll
    for (int j = 0; j < 12; j++) acc[a][j] = 0.f;

  for (int tap = 0; tap < 9; tap++){
    const int ky = tap/3, kx = tap - (tap/3)*3;
    __syncthreads();
    if (wpk){
      const u32* wsrc = wpk + tap*4608;
      for (int e = tid; e < 4608; e += 256) wsl[e] = wsrc[e];
    } else {
      for (int e = tid; e < 4608; e += 256){
        int c2 = e/96, o = e - (e/96)*96;
        wsl[e] = pack2(wOIHW[(o*96 + 2*c2)*9 + tap], wOIHW[(o*96 + 2*c2 + 1)*9 + tap]);
      }
    }
    __syncthreads();
    for (int c2 = 0; c2 < 48; c2++){
      u32 iv[4];
      #pragma unroll
      for (int a = 0; a < 4; a++)
        iv[a] = intile[((py8+2*a+ky*DIL)*SX + (px8+kx*DIL))*49 + c2];
      const u32* wr = &wsl[c2*96 + o0];
      uint4 wA = *(const uint4*)(wr);
      uint4 wB = *(const uint4*)(wr+4);
      uint4 wC = *(const uint4*)(wr+8);
      #pragma unroll
      for (int a = 0; a < 4; a++){
        u32 v = iv[a];
        acc[a][0]  = dot2bf(v, wA.x, acc[a][0]);
        acc[a][1]  = dot2bf(v, wA.y, acc[a][1]);
        acc[a][2]  = dot2bf(v, wA.z, acc[a][2]);
        acc[a][3]  = dot2bf(v, wA.w, acc[a][3]);
        acc[a][4]  = dot2bf(v, wB.x, acc[a][4]);
        acc[a][5]  = dot2bf(v, wB.y, acc[a][5]);
        acc[a][6]  = dot2bf(v, wB.z, acc[a][6]);
        acc[a][7]  = dot2bf(v, wB.w, acc[a][7]);
        acc[a][8]  = dot2bf(v, wC.x, acc[a][8]);
        acc[a][9]  = dot2bf(v, wC.y, acc[a][9]);
        acc[a][10] = dot2bf(v, wC.z, acc[a][10]);
        acc[a][11] = dot2bf(v, wC.w, acc[a][11]);
      }
    }
  }
  float sc[12], mm[12], bb[12], cbv[12];
  #pragma unroll
  for (int j = 0; j < 12; j++){
    sc[j] = bng[o0+j]*rsqrtf(bnv[o0+j]+1e-5f);
    mm[j] = bnm[o0+j]; bb[j] = bnb[o0+j]; cbv[j] = cb[o0+j];
  }
  #pragma unroll
  for (int a = 0; a < 4; a++){
    int gy = by + py8 + 2*a, gx = bx + px8;
    size_t base = ((size_t)((b*224+gy)*224+gx))*96 + o0;
    #pragma unroll
    for (int d = 0; d < 6; d++){
      float t0 = (acc[a][2*d]   + cbv[2*d]   - mm[2*d])  *sc[2*d]   + bb[2*d];
      float t1 = (acc[a][2*d+1] + cbv[2*d+1] - mm[2*d+1])*sc[2*d+1] + bb[2*d+1];
      *(u32*)(dst + base + 2*d) = pack2(gelu(t0), gelu(t1));
    }
  }
}

// ---------------------------------------------------------------------------
// K3b: 3x3 conv (dil 2) + bias + BN + GELU + residual(x2), dot2 (unchanged).
// ---------------------------------------------------------------------------
__global__ __launch_bounds__(256,2) void conv2_k(
    const u16* __restrict__ src, const u32* __restrict__ wpk,
    const float* __restrict__ wOIHW,
    const float* __restrict__ cb, const float* __restrict__ bng, const float* __restrict__ bnb,
    const float* __restrict__ bnm, const float* __restrict__ bnv,
    const float* resid, float* dst)
{
  constexpr int DIL = 2, SY = 12, SX = 20;
  __shared__ u32 intile[SY*SX*49];
  __shared__ __align__(16) u32 wsl[4608];
  const int tid = threadIdx.x;
  const int bx = blockIdx.x*16, by = blockIdx.y*8, b = blockIdx.z;
  const int gy0 = by - DIL, gx0 = bx - DIL;
  for (int e = tid; e < SY*SX*48; e += 256){
    int p = e/48, c2 = e - (e/48)*48;
    int y = p/SX, xx = p - (p/SX)*SX;
    int gy = gy0+y, gx = gx0+xx;
    u32 v = 0;
    if (gy >= 0 && gy < 224 && gx >= 0 && gx < 224)
      v = *(const u32*)(src + ((size_t)((b*224+gy)*224+gx))*96 + c2*2);
    intile[p*49 + c2] = v;
  }
  const int pxg = tid & 31, og = tid >> 5;
  const int px8 = pxg & 15, py8 = pxg >> 4;
  const int o0 = og*12;
  float acc[4][12];
  #pragma unroll
  for (int a = 0; a < 4; a++)
    #pragma unroll
    for (int j = 0; j < 12; j++) acc[a][j] = 0.f;

  for (int tap = 0; tap < 9; tap++){
    const int ky = tap/3, kx = tap - (tap/3)*3;
    __syncthreads();
    if (wpk){
      const u32* wsrc = wpk + tap*4608;
      for (int e = tid; e < 4608; e += 256) wsl[e] = wsrc[e];
    } else {
      for (int e = tid; e < 4608; e += 256){
        int c2 = e/96, o = e - (e/96)*96;
        wsl[e] = pack2(wOIHW[(o*96 + 2*c2)*9 + tap], wOIHW[(o*96 + 2*c2 + 1)*9 + tap]);
      }
    }
    __syncthreads();
    for (int c2 = 0; c2 < 48; c2++){
      u32 iv[4];
      #pragma unroll
      for (int a = 0; a < 4; a++)
        iv[a] = intile[((py8+2*a+ky*DIL)*SX + (px8+kx*DIL))*49 + c2];
      const u32* wr = &wsl[c2*96 + o0];
      uint4 wA = *(const uint4*)(wr);
      uint4 wB = *(const uint4*)(wr+4);
      uint4 wC = *(const uint4*)(wr+8);
      #pragma unroll
      for (int a = 0; a < 4; a++){
        u32 v = iv[a];
        acc[a][0]  = dot2bf(v, wA.x, acc[a][0]);
        acc[a][1]  = dot2bf(v, wA.y, acc[a][1]);
        acc[a][2]  = dot2bf(v, wA.z, acc[a][2]);
        acc[a][3]  = dot2bf(v, wA.w, acc[a][3]);
        acc[a][4]  = dot2bf(v, wB.x, acc[a][4]);
        acc[a][5]  = dot2bf(v, wB.y, acc[a][5]);
        acc[a][6]  = dot2bf(v, wB.z, acc[a][6]);
        acc[a][7]  = dot2bf(v, wB.w, acc[a][7]);
        acc[a][8]  = dot2bf(v, wC.x, acc[a][8]);
        acc[a][9]  = dot2bf(v, wC.y, acc[a][9]);
        acc[a][10] = dot2bf(v, wC.z, acc[a][10]);
        acc[a][11] = dot2bf(v, wC.w, acc[a][11]);
      }
    }
  }
  float sc[12], mm[12], bb[12], cbv[12];
  #pragma unroll
  for (int j = 0; j < 12; j++){
    sc[j] = bng[o0+j]*rsqrtf(bnv[o0+j]+1e-5f);
    mm[j] = bnm[o0+j]; bb[j] = bnb[o0+j]; cbv[j] = cb[o0+j];
  }
  #pragma unroll
  for (int a = 0; a < 4; a++){
    int gy = by + py8 + 2*a, gx = bx + px8;
    size_t base = ((size_t)((b*224+gy)*224+gx))*96 + o0;
    float4 r0 = *(const float4*)(resid + base);
    float4 r1 = *(const float4*)(resid + base + 4);
    float4 r2 = *(const float4*)(resid + base + 8);
    float ov[12];
    #pragma unroll
    for (int j = 0; j < 12; j++){
      float t = (acc[a][j] + cbv[j] - mm[j])*sc[j] + bb[j];
      ov[j] = gelu(t);
    }
    float4 s0, s1, s2;
    s0.x = ov[0]+r0.x;  s0.y = ov[1]+r0.y;  s0.z = ov[2]+r0.z;  s0.w = ov[3]+r0.w;
    s1.x = ov[4]+r1.x;  s1.y = ov[5]+r1.y;  s1.z = ov[6]+r1.z;  s1.w = ov[7]+r1.w;
    s2.x = ov[8]+r2.x;  s2.y = ov[9]+r2.y;  s2.z = ov[10]+r2.z; s2.w = ov[11]+r2.w;
    *(float4*)(dst + base)     = s0;
    *(float4*)(dst + base + 4) = s1;
    *(float4*)(dst + base + 8) = s2;
  }
}

// ---------------------------------------------------------------------------
extern "C" void kernel_launch(void* const* d_in, const int* in_sizes, int n_in,
                              void* d_out, int out_size, void* d_ws, size_t ws_size,
                              hipStream_t stream)
{
  const float* x    = (const float*)d_in[0];
  const float* ndwi = (const float*)d_in[1];
  const float* n1g  = (const float*)d_in[2];
  const float* n1b  = (const float*)d_in[3];
  const float* qkvw = (const float*)d_in[4];
  const float* qkvb = (const float*)d_in[5];
  const float* projw= (const float*)d_in[6];
  const float* projb= (const float*)d_in[7];
  const float* rpbt = (const float*)d_in[8];
  const float* n2g  = (const float*)d_in[9];
  const float* n2b  = (const float*)d_in[10];
  const float* w1   = (const float*)d_in[11];
  const float* b1   = (const float*)d_in[12];
  const float* w2   = (const float*)d_in[13];
  const float* b2   = (const float*)d_in[14];
  const float* n3g  = (const float*)d_in[15];
  const float* n3b  = (const float*)d_in[16];
  const float* c1w  = (const float*)d_in[17];
  const float* c1b  = (const float*)d_in[18];
  const float* bn1g = (const float*)d_in[19];
  const float* bn1b = (const float*)d_in[20];
  const float* bn1m = (const float*)d_in[21];
  const float* bn1v = (const float*)d_in[22];
  const float* c2w  = (const float*)d_in[23];
  const float* c2b  = (const float*)d_in[24];
  const float* bn2g = (const float*)d_in[25];
  const float* bn2b = (const float*)d_in[26];
  const float* bn2m = (const float*)d_in[27];
  const float* bn2v = (const float*)d_in[28];

  int B = out_size / (224*224*96);
  if (B < 1 || B > 64) B = 4;
  const size_t elems = (size_t)B*224*224*96;

  u16*   wsA = (u16*)d_ws;
  u32*   w8q = (u32*)d_out;
  u32*   w8p = w8q + 13824;
  float* xo  = (float*)d_out;
  u32*   wcv = nullptr;
  if (ws_size >= elems*sizeof(u16) + 82944*sizeof(u32))
    wcv = (u32*)(wsA + elems);

  wprep_k<<<dim3(72), dim3(256), 0, stream>>>(qkvw, projw, w8q, w8p);
  if (wcv) wprep_cv<<<dim3(324), dim3(256), 0, stream>>>(c1w, c2w, wcv);
  attn_k<<<dim3(B*1024), dim3(256), 0, stream>>>(x, ndwi, n1g, n1b, w8q, qkvb, w8p, projb, rpbt, wsA);
  mlp_k<<<dim3(B*784), dim3(256), 0, stream>>>(wsA, w1, b1, w2, b2, n2g, n2b, xo);
  conv1_k<<<dim3(14,28,B), dim3(256), 0, stream>>>(xo, wcv, c1w, c1b, bn1g, bn1b, bn1m, bn1v, n3g, n3b, wsA);
  conv2_k<<<dim3(14,28,B), dim3(256), 0, stream>>>(wsA, wcv ? wcv + 41472 : nullptr, c2w, c2b, bn2g, bn2b, bn2m, bn2v, xo, xo);
}